// Round 6
// baseline (161.168 us; speedup 1.0000x reference)
//
#include <hip/hip_runtime.h>
#include <hip/hip_bf16.h>
#include <math.h>

#define B_SZ 16384
#define C_SZ 2048
#define D_SZ 128
#define MAXP 256

typedef float f32x4 __attribute__((ext_vector_type(4)));
typedef short short8 __attribute__((ext_vector_type(8)));

// ---- workspace layout (bytes) ----
// 0        : pos_count[C]     int   (8192)
// 8192     : acc[2]           float (8)
// 8200     : ticket           int   (4)
// 8448     : pos_list[C*MAXP] int   (2 MB)   -> 2,105,600
// 2105600  : pnh [C*D] bf16 (512KB) -> 2,629,888
// 2629888  : pnl [C*D] bf16 (512KB) -> 3,154,176
// 3154176  : enh [C*D] bf16 (512KB) -> 3,678,464
// 3678464  : enl [C*D] bf16 (512KB) -> 4,202,752
// 4202752  : tab[C] f32 (8KB)       -> 4,210,944
// 4210944  : sim[C*C] f32 (16MB)    -> 20,988,160
// 20988160 : cosm[C*C] f32 (16MB)   -> 37,765,376

// blocks 0..2047: L2-normalize class_emb -> en(h,l) + tab
// blocks 2048+  : zero pos_count/acc/ticket (2112 dwords)
__global__ __launch_bounds__(128) void k_pre(const float* __restrict__ class_emb,
                                             const float* __restrict__ tempPtr,
                                             __hip_bfloat16* __restrict__ enh,
                                             __hip_bfloat16* __restrict__ enl,
                                             float* __restrict__ tab,
                                             unsigned* __restrict__ zr) {
    if (blockIdx.x >= C_SZ) {
        int t = (blockIdx.x - C_SZ) * 128 + threadIdx.x;
        if (t < 2112) zr[t] = 0u;
        return;
    }
    int c = blockIdx.x;
    int d = threadIdx.x;
    __shared__ float s_w[2];
    float v = class_emb[c * D_SZ + d];
    float sq = v * v;
#pragma unroll
    for (int off = 32; off >= 1; off >>= 1) sq += __shfl_xor(sq, off);
    if ((d & 63) == 0) s_w[d >> 6] = sq;
    __syncthreads();
    float tot = s_w[0] + s_w[1];
    float vn = v * rsqrtf(tot + 1e-12f);
    __hip_bfloat16 h = __float2bfloat16(vn);
    enh[c * D_SZ + d] = h;
    enl[c * D_SZ + d] = __float2bfloat16(vn - __bfloat162float(h));
    if (d == 0) tab[c] = 1.0f / (tempPtr[0] * logf((float)c + 2.0f));
}

__global__ __launch_bounds__(256) void k_scan(const float* __restrict__ targets,
                                              int* __restrict__ pos_count,
                                              int* __restrict__ pos_list) {
    int tid = blockIdx.x * blockDim.x + threadIdx.x;
    int total = (B_SZ * C_SZ) >> 2;
    int stride = gridDim.x * blockDim.x;
    for (int v = tid; v < total; v += stride) {
        float4 t = ((const float4*)targets)[v];
        if (t.x != 0.f || t.y != 0.f || t.z != 0.f || t.w != 0.f) {
            int e0 = v << 2;
            int b = e0 >> 11;
            int c0 = e0 & (C_SZ - 1);
            float vals[4] = {t.x, t.y, t.z, t.w};
#pragma unroll
            for (int q = 0; q < 4; ++q) {
                if (vals[q] != 0.f) {
                    int c = c0 + q;
                    int slot = atomicAdd(&pos_count[c], 1);
                    if (slot < MAXP) pos_list[c * MAXP + slot] = b;
                }
            }
        }
    }
}

// masked mean pool + L2 norm -> pn(h,l)
__global__ __launch_bounds__(128) void k_pool(const float* __restrict__ output,
                                              const int* __restrict__ pos_count,
                                              const int* __restrict__ pos_list,
                                              __hip_bfloat16* __restrict__ pnh,
                                              __hip_bfloat16* __restrict__ pnl) {
    int c = blockIdx.x;
    int d = threadIdx.x;
    __shared__ float s_w[2];
    int n = pos_count[c];
    if (n > MAXP) n = MAXP;
    float acc = 0.f, cnt = 0.f;
    for (int k = 0; k < n; ++k) {
        int b = pos_list[c * MAXP + k];
        float v = output[b * D_SZ + d];
        acc += v;
        cnt += (v != 0.f) ? 1.f : 0.f;
    }
    float pooled = acc / (cnt + 1e-9f);
    float sq = pooled * pooled;
#pragma unroll
    for (int off = 32; off >= 1; off >>= 1) sq += __shfl_xor(sq, off);
    if ((d & 63) == 0) s_w[d >> 6] = sq;
    __syncthreads();
    float tot = s_w[0] + s_w[1];
    float vn = pooled * rsqrtf(tot + 1e-12f);
    __hip_bfloat16 h = __float2bfloat16(vn);
    pnh[c * D_SZ + d] = h;
    pnl[c * D_SZ + d] = __float2bfloat16(vn - __bfloat162float(h));
}

// Fused: rows 0..2047 = en @ en^T -> sim ; rows 2048..4095 = pn @ en^T -> cosm.
// 64x64 tile, 4 waves (2x2 of 32x32), split-bf16 3-term MFMA, XOR-swizzled LDS.
__global__ __launch_bounds__(256) void k_gemm_mfma(const __hip_bfloat16* __restrict__ enh_p,
                                                   const __hip_bfloat16* __restrict__ enl_p,
                                                   const __hip_bfloat16* __restrict__ pnh_p,
                                                   const __hip_bfloat16* __restrict__ pnl_p,
                                                   float* __restrict__ sim,
                                                   float* __restrict__ cosm) {
    extern __shared__ char smem[];
    char* As = smem;           // 64 rows * 512B: kbyte 0..255 = hi, 256..511 = lo
    char* Bs = smem + 32768;
    const int tid = threadIdx.x;
    const __hip_bfloat16* Ah;
    const __hip_bfloat16* Al;
    float* Out;
    int rb;
    if (blockIdx.y < 32) { Ah = enh_p; Al = enl_p; Out = sim;  rb = blockIdx.y << 6; }
    else                 { Ah = pnh_p; Al = pnl_p; Out = cosm; rb = (blockIdx.y - 32) << 6; }
    const int cb = blockIdx.x << 6;
    {
        int r = tid >> 2;
        int c0 = (tid & 3) << 5;
        int sw = (r & 7) << 4;
#pragma unroll
        for (int j = 0; j < 4; ++j) {
            int c = c0 + (j << 3);
            uint4 vh = *(const uint4*)&Ah[(rb + r) * D_SZ + c];
            *(uint4*)(As + r * 512 + ((2 * c) ^ sw)) = vh;
            uint4 vl = *(const uint4*)&Al[(rb + r) * D_SZ + c];
            *(uint4*)(As + r * 512 + ((512 + 2 * c) ^ sw) - 256) = vl;
            uint4 wh = *(const uint4*)&enh_p[(cb + r) * D_SZ + c];
            *(uint4*)(Bs + r * 512 + ((2 * c) ^ sw)) = wh;
            uint4 wl = *(const uint4*)&enl_p[(cb + r) * D_SZ + c];
            *(uint4*)(Bs + r * 512 + ((512 + 2 * c) ^ sw) - 256) = wl;
        }
    }
    __syncthreads();
    const int w = tid >> 6, lane = tid & 63;
    const int wr = (w >> 1) << 5;
    const int wc = (w & 1) << 5;
    const int lrow = lane & 15;
    const int lk = (lane >> 4) << 4;
    int ar0 = wr + lrow, ar1 = wr + 16 + lrow;
    int br0 = wc + lrow, br1 = wc + 16 + lrow;
    const char* pa0 = As + ar0 * 512; const int swa0 = (ar0 & 7) << 4;
    const char* pa1 = As + ar1 * 512; const int swa1 = (ar1 & 7) << 4;
    const char* pb0 = Bs + br0 * 512; const int swb0 = (br0 & 7) << 4;
    const char* pb1 = Bs + br1 * 512; const int swb1 = (br1 & 7) << 4;
    f32x4 acc00 = {0.f, 0.f, 0.f, 0.f};
    f32x4 acc01 = acc00, acc10 = acc00, acc11 = acc00;
#pragma unroll
    for (int term = 0; term < 3; ++term) {
        const int ao = (term == 2) ? 256 : 0;   // A: hi,hi,lo
        const int bo = (term == 1) ? 256 : 0;   // B: hi,lo,hi
#pragma unroll
        for (int kk = 0; kk < 4; ++kk) {
            const int ka = ao + (kk << 6) + lk;
            const int kb = bo + (kk << 6) + lk;
            short8 a0 = *(const short8*)(pa0 + ((ka & 0x100) | ((ka & 0xFF) ^ swa0)));
            short8 a1 = *(const short8*)(pa1 + ((ka & 0x100) | ((ka & 0xFF) ^ swa1)));
            short8 b0 = *(const short8*)(pb0 + ((kb & 0x100) | ((kb & 0xFF) ^ swb0)));
            short8 b1 = *(const short8*)(pb1 + ((kb & 0x100) | ((kb & 0xFF) ^ swb1)));
            acc00 = __builtin_amdgcn_mfma_f32_16x16x32_bf16(a0, b0, acc00, 0, 0, 0);
            acc01 = __builtin_amdgcn_mfma_f32_16x16x32_bf16(a0, b1, acc01, 0, 0, 0);
            acc10 = __builtin_amdgcn_mfma_f32_16x16x32_bf16(a1, b0, acc10, 0, 0, 0);
            acc11 = __builtin_amdgcn_mfma_f32_16x16x32_bf16(a1, b1, acc11, 0, 0, 0);
        }
    }
    const int crow = rb + wr + ((lane >> 4) << 2);
    const int ccol = cb + wc + lrow;
#pragma unroll
    for (int r = 0; r < 4; ++r) {
        Out[(crow + r) * C_SZ + ccol]           = acc00[r];
        Out[(crow + r) * C_SZ + ccol + 16]      = acc01[r];
        Out[(crow + 16 + r) * C_SZ + ccol]      = acc10[r];
        Out[(crow + 16 + r) * C_SZ + ccol + 16] = acc11[r];
    }
}

// Single-pass bucket-rank -> discounted logits -> log_softmax -> diagonal ->
// loss accumulate; last block (ticket) computes the final mean -> out.
__global__ __launch_bounds__(256) void k_rank_softmax(const float* __restrict__ sim,
                                                      const float* __restrict__ cosm,
                                                      const int* __restrict__ pos_count,
                                                      const float* __restrict__ tab,
                                                      float* __restrict__ acc,
                                                      int* __restrict__ ticket,
                                                      float* __restrict__ outp) {
    int i = blockIdx.x;
    const int tid = threadIdx.x;
    const bool valid = pos_count[i] != 0;
    if (valid) {
        __shared__ unsigned long long s_pairs[C_SZ];  // 16 KB
        __shared__ unsigned s_hist[C_SZ];             // 8 KB
        __shared__ int s_wt[4];
        __shared__ float s_red[4];
        __shared__ float s_diag;
        const int lane = tid & 63;
        const int w = tid >> 6;
        const int base = tid << 3;

        float4 sa = *(const float4*)&sim[i * C_SZ + base];
        float4 sb = *(const float4*)&sim[i * C_SZ + base + 4];
        float4 ca = *(const float4*)&cosm[i * C_SZ + base];
        float4 cb = *(const float4*)&cosm[i * C_SZ + base + 4];
        uint4 z4 = {0u, 0u, 0u, 0u};
        ((uint4*)s_hist)[tid] = z4;
        ((uint4*)s_hist)[tid + 256] = z4;

        float xs[8] = {sa.x, sa.y, sa.z, sa.w, sb.x, sb.y, sb.z, sb.w};
        unsigned uk[8];
        int bk[8];
#pragma unroll
        for (int e = 0; e < 8; ++e) {
            unsigned u = __float_as_uint(xs[e]);
            u = (u & 0x80000000u) ? ~u : (u | 0x80000000u);
            if (u == 0x7FFFFFFFu) u = 0x80000000u;   // -0.0 == +0.0
            uk[e] = u;
            int b = (int)((xs[e] + 1.0f) * 1023.5f);
            bk[e] = b < 0 ? 0 : (b > 2047 ? 2047 : b);
        }
        __syncthreads();
#pragma unroll
        for (int e = 0; e < 8; ++e) atomicAdd(&s_hist[bk[e]], 1u);
        __syncthreads();
        uint4 h0 = ((const uint4*)s_hist)[2 * tid];
        uint4 h1 = ((const uint4*)s_hist)[2 * tid + 1];
        unsigned hv[8] = {h0.x, h0.y, h0.z, h0.w, h1.x, h1.y, h1.z, h1.w};
        unsigned excl[8];
        unsigned sum = 0;
#pragma unroll
        for (int j = 0; j < 8; ++j) { excl[j] = sum; sum += hv[j]; }
        int incl = (int)sum;
#pragma unroll
        for (int off = 1; off < 64; off <<= 1) {
            int o = __shfl_up(incl, off);
            if (lane >= off) incl += o;
        }
        if (lane == 63) s_wt[w] = incl;
        __syncthreads();
        int wbase = 0;
#pragma unroll
        for (int ww = 0; ww < 4; ++ww) wbase += (ww < w) ? s_wt[ww] : 0;
        unsigned ebase = (unsigned)(wbase + incl - (int)sum);
        uint4 w0 = {excl[0] + ebase, excl[1] + ebase, excl[2] + ebase, excl[3] + ebase};
        uint4 w1 = {excl[4] + ebase, excl[5] + ebase, excl[6] + ebase, excl[7] + ebase};
        ((uint4*)s_hist)[2 * tid] = w0;
        ((uint4*)s_hist)[2 * tid + 1] = w1;
        __syncthreads();
        unsigned long long mypair[8];
#pragma unroll
        for (int e = 0; e < 8; ++e) {
            unsigned long long pr = ((unsigned long long)uk[e] << 32) | (unsigned)(base + e);
            mypair[e] = pr;
            unsigned pos = atomicAdd(&s_hist[bk[e]], 1u);
            s_pairs[pos] = pr;
        }
        __syncthreads();
        int rk[8];
#pragma unroll
        for (int e = 0; e < 8; ++e) {
            int b = bk[e];
            int end = (int)s_hist[b];
            int start = b ? (int)s_hist[b - 1] : 0;
            unsigned long long me = mypair[e];
            int cnt = 0;
            for (int j = start; j < end; ++j) cnt += (s_pairs[j] < me) ? 1 : 0;
            rk[e] = start + cnt;
        }
        float cs[8] = {ca.x, ca.y, ca.z, ca.w, cb.x, cb.y, cb.z, cb.w};
        float lg[8];
        float lmax = -3.4e38f;
#pragma unroll
        for (int e = 0; e < 8; ++e) {
            lg[e] = cs[e] * tab[rk[e]];
            lmax = fmaxf(lmax, lg[e]);
        }
        if ((i >> 3) == tid) {
            int ei = i & 7;
            float dv = lg[0];
#pragma unroll
            for (int e = 1; e < 8; ++e) dv = (ei == e) ? lg[e] : dv;
            s_diag = dv;
        }
#pragma unroll
        for (int off = 1; off < 64; off <<= 1) lmax = fmaxf(lmax, __shfl_xor(lmax, off));
        if (lane == 0) s_red[w] = lmax;
        __syncthreads();
        float m = fmaxf(fmaxf(s_red[0], s_red[1]), fmaxf(s_red[2], s_red[3]));
        float lsum = 0.f;
#pragma unroll
        for (int e = 0; e < 8; ++e) lsum += __expf(lg[e] - m);
#pragma unroll
        for (int off = 1; off < 64; off <<= 1) lsum += __shfl_xor(lsum, off);
        __syncthreads();
        if (lane == 0) s_red[w] = lsum;
        __syncthreads();
        if (tid == 0) {
            float tot = s_red[0] + s_red[1] + s_red[2] + s_red[3];
            float pos_lp = s_diag - m - logf(tot);
            atomicAdd(&acc[0], -pos_lp);
            atomicAdd(&acc[1], 1.0f);
        }
    }
    // all blocks: completion ticket; last block finalizes
    if (tid == 0) {
        __threadfence();
        int old = atomicAdd(ticket, 1);
        if (old == C_SZ - 1) {
            float s = atomicAdd(&acc[0], 0.0f);
            float n = atomicAdd(&acc[1], 0.0f);
            outp[0] = s / fmaxf(n, 1.0f);
        }
    }
}

extern "C" void kernel_launch(void* const* d_in, const int* in_sizes, int n_in,
                              void* d_out, int out_size, void* d_ws, size_t ws_size,
                              hipStream_t stream) {
    const float* output    = (const float*)d_in[0];
    const float* class_emb = (const float*)d_in[1];
    const float* targets   = (const float*)d_in[2];
    const float* tempPtr   = (const float*)d_in[3];
    float* out = (float*)d_out;
    char* ws = (char*)d_ws;

    int*   pos_count = (int*)(ws + 0);
    float* acc       = (float*)(ws + 8192);
    int*   ticket    = (int*)(ws + 8200);
    int*   pos_list  = (int*)(ws + 8448);
    __hip_bfloat16* pnh = (__hip_bfloat16*)(ws + 2105600);
    __hip_bfloat16* pnl = (__hip_bfloat16*)(ws + 2629888);
    __hip_bfloat16* enh = (__hip_bfloat16*)(ws + 3154176);
    __hip_bfloat16* enl = (__hip_bfloat16*)(ws + 3678464);
    float* tab       = (float*)(ws + 4202752);
    float* sim       = (float*)(ws + 4210944);
    float* cosm      = (float*)(ws + 20988160);

    k_pre<<<C_SZ + 17, 128, 0, stream>>>(class_emb, tempPtr, enh, enl, tab, (unsigned*)ws);
    k_scan<<<4096, 256, 0, stream>>>(targets, pos_count, pos_list);
    k_pool<<<C_SZ, 128, 0, stream>>>(output, pos_count, pos_list, pnh, pnl);
    dim3 g(C_SZ / 64, 2 * C_SZ / 64);
    k_gemm_mfma<<<g, 256, 65536, stream>>>(enh, enl, pnh, pnl, sim, cosm);
    k_rank_softmax<<<C_SZ, 256, 0, stream>>>(sim, cosm, pos_count, tab, acc, ticket, out);
}

// Round 7
// 131.817 us; speedup vs baseline: 1.2227x; 1.2227x over previous
//
#include <hip/hip_runtime.h>
#include <hip/hip_bf16.h>
#include <math.h>

#define B_SZ 16384
#define C_SZ 2048
#define D_SZ 128
#define MAXP 256

typedef float f32x4 __attribute__((ext_vector_type(4)));
typedef short short8 __attribute__((ext_vector_type(8)));

// ---- workspace layout (bytes) ----
// 0        : pos_count[C]     int   (8192)
// 8192     : acc[2]           float (8)
// 8448     : pos_list[C*MAXP] int   (2 MB)   -> 2,105,600
// 2105600  : pnh [C*D] bf16 (512KB) -> 2,629,888
// 2629888  : pnl [C*D] bf16 (512KB) -> 3,154,176
// 3154176  : enh [C*D] bf16 (512KB) -> 3,678,464
// 3678464  : enl [C*D] bf16 (512KB) -> 4,202,752
// 4202752  : tab[C] f32 (8KB)       -> 4,210,944
// 4210944  : sim[C*C] f32 (16MB)    -> 20,988,160
// 20988160 : cosm[C*C] f32 (16MB)   -> 37,765,376

// blocks 0..2047: L2-normalize class_emb -> en(h,l) + tab
// blocks 2048+  : zero pos_count/acc (2050 dwords)
__global__ __launch_bounds__(128) void k_pre(const float* __restrict__ class_emb,
                                             const float* __restrict__ tempPtr,
                                             __hip_bfloat16* __restrict__ enh,
                                             __hip_bfloat16* __restrict__ enl,
                                             float* __restrict__ tab,
                                             unsigned* __restrict__ zr) {
    if (blockIdx.x >= C_SZ) {
        int t = (blockIdx.x - C_SZ) * 128 + threadIdx.x;
        if (t < 2112) zr[t] = 0u;
        return;
    }
    int c = blockIdx.x;
    int d = threadIdx.x;
    __shared__ float s_w[2];
    float v = class_emb[c * D_SZ + d];
    float sq = v * v;
#pragma unroll
    for (int off = 32; off >= 1; off >>= 1) sq += __shfl_xor(sq, off);
    if ((d & 63) == 0) s_w[d >> 6] = sq;
    __syncthreads();
    float tot = s_w[0] + s_w[1];
    float vn = v * rsqrtf(tot + 1e-12f);
    __hip_bfloat16 h = __float2bfloat16(vn);
    enh[c * D_SZ + d] = h;
    enl[c * D_SZ + d] = __float2bfloat16(vn - __bfloat162float(h));
    if (d == 0) tab[c] = 1.0f / (tempPtr[0] * logf((float)c + 2.0f));
}

__global__ __launch_bounds__(256) void k_scan(const float* __restrict__ targets,
                                              int* __restrict__ pos_count,
                                              int* __restrict__ pos_list) {
    int tid = blockIdx.x * blockDim.x + threadIdx.x;
    int total = (B_SZ * C_SZ) >> 2;
    int stride = gridDim.x * blockDim.x;
    for (int v = tid; v < total; v += stride) {
        float4 t = ((const float4*)targets)[v];
        if (t.x != 0.f || t.y != 0.f || t.z != 0.f || t.w != 0.f) {
            int e0 = v << 2;
            int b = e0 >> 11;
            int c0 = e0 & (C_SZ - 1);
            float vals[4] = {t.x, t.y, t.z, t.w};
#pragma unroll
            for (int q = 0; q < 4; ++q) {
                if (vals[q] != 0.f) {
                    int c = c0 + q;
                    int slot = atomicAdd(&pos_count[c], 1);
                    if (slot < MAXP) pos_list[c * MAXP + slot] = b;
                }
            }
        }
    }
}

// masked mean pool + L2 norm -> pn(h,l)
__global__ __launch_bounds__(128) void k_pool(const float* __restrict__ output,
                                              const int* __restrict__ pos_count,
                                              const int* __restrict__ pos_list,
                                              __hip_bfloat16* __restrict__ pnh,
                                              __hip_bfloat16* __restrict__ pnl) {
    int c = blockIdx.x;
    int d = threadIdx.x;
    __shared__ float s_w[2];
    int n = pos_count[c];
    if (n > MAXP) n = MAXP;
    float acc = 0.f, cnt = 0.f;
    for (int k = 0; k < n; ++k) {
        int b = pos_list[c * MAXP + k];
        float v = output[b * D_SZ + d];
        acc += v;
        cnt += (v != 0.f) ? 1.f : 0.f;
    }
    float pooled = acc / (cnt + 1e-9f);
    float sq = pooled * pooled;
#pragma unroll
    for (int off = 32; off >= 1; off >>= 1) sq += __shfl_xor(sq, off);
    if ((d & 63) == 0) s_w[d >> 6] = sq;
    __syncthreads();
    float tot = s_w[0] + s_w[1];
    float vn = pooled * rsqrtf(tot + 1e-12f);
    __hip_bfloat16 h = __float2bfloat16(vn);
    pnh[c * D_SZ + d] = h;
    pnl[c * D_SZ + d] = __float2bfloat16(vn - __bfloat162float(h));
}

// Fused: rows 0..2047 = en @ en^T -> sim ; rows 2048..4095 = pn @ en^T -> cosm.
__global__ __launch_bounds__(256) void k_gemm_mfma(const __hip_bfloat16* __restrict__ enh_p,
                                                   const __hip_bfloat16* __restrict__ enl_p,
                                                   const __hip_bfloat16* __restrict__ pnh_p,
                                                   const __hip_bfloat16* __restrict__ pnl_p,
                                                   float* __restrict__ sim,
                                                   float* __restrict__ cosm) {
    extern __shared__ char smem[];
    char* As = smem;           // 64 rows * 512B: kbyte 0..255 = hi, 256..511 = lo
    char* Bs = smem + 32768;
    const int tid = threadIdx.x;
    const __hip_bfloat16* Ah;
    const __hip_bfloat16* Al;
    float* Out;
    int rb;
    if (blockIdx.y < 32) { Ah = enh_p; Al = enl_p; Out = sim;  rb = blockIdx.y << 6; }
    else                 { Ah = pnh_p; Al = pnl_p; Out = cosm; rb = (blockIdx.y - 32) << 6; }
    const int cb = blockIdx.x << 6;
    {
        int r = tid >> 2;
        int c0 = (tid & 3) << 5;
        int sw = (r & 7) << 4;
#pragma unroll
        for (int j = 0; j < 4; ++j) {
            int c = c0 + (j << 3);
            uint4 vh = *(const uint4*)&Ah[(rb + r) * D_SZ + c];
            *(uint4*)(As + r * 512 + ((2 * c) ^ sw)) = vh;
            uint4 vl = *(const uint4*)&Al[(rb + r) * D_SZ + c];
            *(uint4*)(As + r * 512 + ((512 + 2 * c) ^ sw) - 256) = vl;
            uint4 wh = *(const uint4*)&enh_p[(cb + r) * D_SZ + c];
            *(uint4*)(Bs + r * 512 + ((2 * c) ^ sw)) = wh;
            uint4 wl = *(const uint4*)&enl_p[(cb + r) * D_SZ + c];
            *(uint4*)(Bs + r * 512 + ((512 + 2 * c) ^ sw) - 256) = wl;
        }
    }
    __syncthreads();
    const int w = tid >> 6, lane = tid & 63;
    const int wr = (w >> 1) << 5;
    const int wc = (w & 1) << 5;
    const int lrow = lane & 15;
    const int lk = (lane >> 4) << 4;
    int ar0 = wr + lrow, ar1 = wr + 16 + lrow;
    int br0 = wc + lrow, br1 = wc + 16 + lrow;
    const char* pa0 = As + ar0 * 512; const int swa0 = (ar0 & 7) << 4;
    const char* pa1 = As + ar1 * 512; const int swa1 = (ar1 & 7) << 4;
    const char* pb0 = Bs + br0 * 512; const int swb0 = (br0 & 7) << 4;
    const char* pb1 = Bs + br1 * 512; const int swb1 = (br1 & 7) << 4;
    f32x4 acc00 = {0.f, 0.f, 0.f, 0.f};
    f32x4 acc01 = acc00, acc10 = acc00, acc11 = acc00;
#pragma unroll
    for (int term = 0; term < 3; ++term) {
        const int ao = (term == 2) ? 256 : 0;   // A: hi,hi,lo
        const int bo = (term == 1) ? 256 : 0;   // B: hi,lo,hi
#pragma unroll
        for (int kk = 0; kk < 4; ++kk) {
            const int ka = ao + (kk << 6) + lk;
            const int kb = bo + (kk << 6) + lk;
            short8 a0 = *(const short8*)(pa0 + ((ka & 0x100) | ((ka & 0xFF) ^ swa0)));
            short8 a1 = *(const short8*)(pa1 + ((ka & 0x100) | ((ka & 0xFF) ^ swa1)));
            short8 b0 = *(const short8*)(pb0 + ((kb & 0x100) | ((kb & 0xFF) ^ swb0)));
            short8 b1 = *(const short8*)(pb1 + ((kb & 0x100) | ((kb & 0xFF) ^ swb1)));
            acc00 = __builtin_amdgcn_mfma_f32_16x16x32_bf16(a0, b0, acc00, 0, 0, 0);
            acc01 = __builtin_amdgcn_mfma_f32_16x16x32_bf16(a0, b1, acc01, 0, 0, 0);
            acc10 = __builtin_amdgcn_mfma_f32_16x16x32_bf16(a1, b0, acc10, 0, 0, 0);
            acc11 = __builtin_amdgcn_mfma_f32_16x16x32_bf16(a1, b1, acc11, 0, 0, 0);
        }
    }
    const int crow = rb + wr + ((lane >> 4) << 2);
    const int ccol = cb + wc + lrow;
#pragma unroll
    for (int r = 0; r < 4; ++r) {
        Out[(crow + r) * C_SZ + ccol]           = acc00[r];
        Out[(crow + r) * C_SZ + ccol + 16]      = acc01[r];
        Out[(crow + 16 + r) * C_SZ + ccol]      = acc10[r];
        Out[(crow + 16 + r) * C_SZ + ccol + 16] = acc11[r];
    }
}

// Single-pass bucket-rank @ 512 threads, 4 elems/thread: histogram -> scan ->
// scatter -> rank -> discounted logits -> log_softmax -> diagonal -> loss.
__global__ __launch_bounds__(512) void k_rank_softmax(const float* __restrict__ sim,
                                                      const float* __restrict__ cosm,
                                                      const int* __restrict__ pos_count,
                                                      const float* __restrict__ tab,
                                                      float* __restrict__ acc) {
    int i = blockIdx.x;
    if (pos_count[i] == 0) return;
    __shared__ unsigned long long s_pairs[C_SZ];  // 16 KB
    __shared__ unsigned s_hist[C_SZ];             // 8 KB
    __shared__ int s_wt[8];
    __shared__ float s_redm[8];
    __shared__ float s_reds[8];
    __shared__ float s_diag;
    const int tid = threadIdx.x;     // 0..511
    const int lane = tid & 63;
    const int w = tid >> 6;          // 0..7
    const int base = tid << 2;       // 4 elems/thread

    float4 sa = *(const float4*)&sim[i * C_SZ + base];
    float4 ca = *(const float4*)&cosm[i * C_SZ + base];
    uint4 z4 = {0u, 0u, 0u, 0u};
    ((uint4*)s_hist)[tid] = z4;

    float xs[4] = {sa.x, sa.y, sa.z, sa.w};
    unsigned uk[4];
    int bk[4];
#pragma unroll
    for (int e = 0; e < 4; ++e) {
        unsigned u = __float_as_uint(xs[e]);
        u = (u & 0x80000000u) ? ~u : (u | 0x80000000u);
        if (u == 0x7FFFFFFFu) u = 0x80000000u;   // -0.0 == +0.0
        uk[e] = u;
        int b = (int)((xs[e] + 1.0f) * 1023.5f);
        bk[e] = b < 0 ? 0 : (b > 2047 ? 2047 : b);
    }
    __syncthreads();
#pragma unroll
    for (int e = 0; e < 4; ++e) atomicAdd(&s_hist[bk[e]], 1u);
    __syncthreads();
    // exclusive scan of 2048 counts (4 contiguous per thread)
    uint4 h0 = ((const uint4*)s_hist)[tid];
    unsigned hv[4] = {h0.x, h0.y, h0.z, h0.w};
    unsigned excl[4];
    unsigned sum = 0;
#pragma unroll
    for (int j = 0; j < 4; ++j) { excl[j] = sum; sum += hv[j]; }
    int incl = (int)sum;
#pragma unroll
    for (int off = 1; off < 64; off <<= 1) {
        int o = __shfl_up(incl, off);
        if (lane >= off) incl += o;
    }
    if (lane == 63) s_wt[w] = incl;
    __syncthreads();
    int wbase = 0;
#pragma unroll
    for (int ww = 0; ww < 8; ++ww) wbase += (ww < w) ? s_wt[ww] : 0;
    unsigned ebase = (unsigned)(wbase + incl - (int)sum);
    uint4 w0 = {excl[0] + ebase, excl[1] + ebase, excl[2] + ebase, excl[3] + ebase};
    ((uint4*)s_hist)[tid] = w0;
    __syncthreads();
    // scatter pairs grouped by bucket (intra-bucket order irrelevant)
    unsigned long long mypair[4];
#pragma unroll
    for (int e = 0; e < 4; ++e) {
        unsigned long long pr = ((unsigned long long)uk[e] << 32) | (unsigned)(base + e);
        mypair[e] = pr;
        unsigned pos = atomicAdd(&s_hist[bk[e]], 1u);
        s_pairs[pos] = pr;
    }
    __syncthreads();
    // ranks: post-scatter s_hist[b] == end[b]; start[b] = b ? s_hist[b-1] : 0
    int rk[4];
#pragma unroll
    for (int e = 0; e < 4; ++e) {
        int b = bk[e];
        int end = (int)s_hist[b];
        int start = b ? (int)s_hist[b - 1] : 0;
        unsigned long long me = mypair[e];
        int cnt = 0;
        for (int j = start; j < end; ++j) cnt += (s_pairs[j] < me) ? 1 : 0;
        rk[e] = start + cnt;
    }
    float cs[4] = {ca.x, ca.y, ca.z, ca.w};
    float lg[4];
    float lmax = -3.4e38f;
#pragma unroll
    for (int e = 0; e < 4; ++e) {
        lg[e] = cs[e] * tab[rk[e]];
        lmax = fmaxf(lmax, lg[e]);
    }
    if ((i >> 2) == tid) {
        int ei = i & 3;
        float dv = lg[0];
#pragma unroll
        for (int e = 1; e < 4; ++e) dv = (ei == e) ? lg[e] : dv;
        s_diag = dv;
    }
#pragma unroll
    for (int off = 1; off < 64; off <<= 1) lmax = fmaxf(lmax, __shfl_xor(lmax, off));
    if (lane == 0) s_redm[w] = lmax;
    __syncthreads();
    float m = s_redm[0];
#pragma unroll
    for (int ww = 1; ww < 8; ++ww) m = fmaxf(m, s_redm[ww]);
    float lsum = 0.f;
#pragma unroll
    for (int e = 0; e < 4; ++e) lsum += __expf(lg[e] - m);
#pragma unroll
    for (int off = 1; off < 64; off <<= 1) lsum += __shfl_xor(lsum, off);
    if (lane == 0) s_reds[w] = lsum;
    __syncthreads();
    if (tid == 0) {
        float tot = 0.f;
#pragma unroll
        for (int ww = 0; ww < 8; ++ww) tot += s_reds[ww];
        float pos_lp = s_diag - m - logf(tot);
        atomicAdd(&acc[0], -pos_lp);
        atomicAdd(&acc[1], 1.0f);
    }
}

__global__ void k_final(const float* __restrict__ acc, float* __restrict__ out) {
    out[0] = acc[0] / fmaxf(acc[1], 1.0f);
}

extern "C" void kernel_launch(void* const* d_in, const int* in_sizes, int n_in,
                              void* d_out, int out_size, void* d_ws, size_t ws_size,
                              hipStream_t stream) {
    const float* output    = (const float*)d_in[0];
    const float* class_emb = (const float*)d_in[1];
    const float* targets   = (const float*)d_in[2];
    const float* tempPtr   = (const float*)d_in[3];
    float* out = (float*)d_out;
    char* ws = (char*)d_ws;

    int*   pos_count = (int*)(ws + 0);
    float* acc       = (float*)(ws + 8192);
    int*   pos_list  = (int*)(ws + 8448);
    __hip_bfloat16* pnh = (__hip_bfloat16*)(ws + 2105600);
    __hip_bfloat16* pnl = (__hip_bfloat16*)(ws + 2629888);
    __hip_bfloat16* enh = (__hip_bfloat16*)(ws + 3154176);
    __hip_bfloat16* enl = (__hip_bfloat16*)(ws + 3678464);
    float* tab       = (float*)(ws + 4202752);
    float* sim       = (float*)(ws + 4210944);
    float* cosm      = (float*)(ws + 20988160);

    k_pre<<<C_SZ + 17, 128, 0, stream>>>(class_emb, tempPtr, enh, enl, tab, (unsigned*)ws);
    k_scan<<<4096, 256, 0, stream>>>(targets, pos_count, pos_list);
    k_pool<<<C_SZ, 128, 0, stream>>>(output, pos_count, pos_list, pnh, pnl);
    dim3 g(C_SZ / 64, 2 * C_SZ / 64);
    k_gemm_mfma<<<g, 256, 65536, stream>>>(enh, enl, pnh, pnl, sim, cosm);
    k_rank_softmax<<<C_SZ, 512, 0, stream>>>(sim, cosm, pos_count, tab, acc);
    k_final<<<1, 1, 0, stream>>>(acc, out);
}

// Round 8
// 111.870 us; speedup vs baseline: 1.4407x; 1.1783x over previous
//
#include <hip/hip_runtime.h>
#include <hip/hip_bf16.h>
#include <math.h>

#define B_SZ 16384
#define C_SZ 2048
#define D_SZ 128
#define MAXP 256

typedef float f32x4 __attribute__((ext_vector_type(4)));
typedef short short8 __attribute__((ext_vector_type(8)));

// ---- workspace layout (bytes) ----
// 0        : pos_count[C]     int   (8192)
// 8192     : acc[2]           float (8)
// 8448     : pos_list[C*MAXP] int   (2 MB)   -> 2,105,600
// 2105600  : pnh [C*D] bf16 (512KB) -> 2,629,888
// 2629888  : pnl [C*D] bf16 (512KB) -> 3,154,176
// 3154176  : enh [C*D] bf16 (512KB) -> 3,678,464
// 3678464  : enl [C*D] bf16 (512KB) -> 4,202,752
// 4202752  : tab[C] f32 (8KB)       -> 4,210,944
// 4210944  : sim[C*C] f32 (16MB)    -> 20,988,160
// 20988160 : cosm[C*C] f32 (16MB)   -> 37,765,376

// blocks 0..2047: L2-normalize class_emb -> en(h,l) + tab
// blocks 2048+  : zero pos_count/acc
__global__ __launch_bounds__(128) void k_pre(const float* __restrict__ class_emb,
                                             const float* __restrict__ tempPtr,
                                             __hip_bfloat16* __restrict__ enh,
                                             __hip_bfloat16* __restrict__ enl,
                                             float* __restrict__ tab,
                                             unsigned* __restrict__ zr) {
    if (blockIdx.x >= C_SZ) {
        int t = (blockIdx.x - C_SZ) * 128 + threadIdx.x;
        if (t < 2112) zr[t] = 0u;
        return;
    }
    int c = blockIdx.x;
    int d = threadIdx.x;
    __shared__ float s_w[2];
    float v = class_emb[c * D_SZ + d];
    float sq = v * v;
#pragma unroll
    for (int off = 32; off >= 1; off >>= 1) sq += __shfl_xor(sq, off);
    if ((d & 63) == 0) s_w[d >> 6] = sq;
    __syncthreads();
    float tot = s_w[0] + s_w[1];
    float vn = v * rsqrtf(tot + 1e-12f);
    __hip_bfloat16 h = __float2bfloat16(vn);
    enh[c * D_SZ + d] = h;
    enl[c * D_SZ + d] = __float2bfloat16(vn - __bfloat162float(h));
    if (d == 0) tab[c] = 1.0f / (tempPtr[0] * logf((float)c + 2.0f));
}

__global__ __launch_bounds__(256) void k_scan(const float* __restrict__ targets,
                                              int* __restrict__ pos_count,
                                              int* __restrict__ pos_list) {
    int tid = blockIdx.x * blockDim.x + threadIdx.x;
    int total = (B_SZ * C_SZ) >> 2;
    int stride = gridDim.x * blockDim.x;
    for (int v = tid; v < total; v += stride) {
        float4 t = ((const float4*)targets)[v];
        if (t.x != 0.f || t.y != 0.f || t.z != 0.f || t.w != 0.f) {
            int e0 = v << 2;
            int b = e0 >> 11;
            int c0 = e0 & (C_SZ - 1);
            float vals[4] = {t.x, t.y, t.z, t.w};
#pragma unroll
            for (int q = 0; q < 4; ++q) {
                if (vals[q] != 0.f) {
                    int c = c0 + q;
                    int slot = atomicAdd(&pos_count[c], 1);
                    if (slot < MAXP) pos_list[c * MAXP + slot] = b;
                }
            }
        }
    }
}

// masked mean pool + L2 norm -> pn(h,l)
__global__ __launch_bounds__(128) void k_pool(const float* __restrict__ output,
                                              const int* __restrict__ pos_count,
                                              const int* __restrict__ pos_list,
                                              __hip_bfloat16* __restrict__ pnh,
                                              __hip_bfloat16* __restrict__ pnl) {
    int c = blockIdx.x;
    int d = threadIdx.x;
    __shared__ float s_w[2];
    int n = pos_count[c];
    if (n > MAXP) n = MAXP;
    float acc = 0.f, cnt = 0.f;
    for (int k = 0; k < n; ++k) {
        int b = pos_list[c * MAXP + k];
        float v = output[b * D_SZ + d];
        acc += v;
        cnt += (v != 0.f) ? 1.f : 0.f;
    }
    float pooled = acc / (cnt + 1e-9f);
    float sq = pooled * pooled;
#pragma unroll
    for (int off = 32; off >= 1; off >>= 1) sq += __shfl_xor(sq, off);
    if ((d & 63) == 0) s_w[d >> 6] = sq;
    __syncthreads();
    float tot = s_w[0] + s_w[1];
    float vn = pooled * rsqrtf(tot + 1e-12f);
    __hip_bfloat16 h = __float2bfloat16(vn);
    pnh[c * D_SZ + d] = h;
    pnl[c * D_SZ + d] = __float2bfloat16(vn - __bfloat162float(h));
}

// Fused: rows 0..2047 = en @ en^T -> sim ; rows 2048..4095 = pn @ en^T -> cosm.
__global__ __launch_bounds__(256) void k_gemm_mfma(const __hip_bfloat16* __restrict__ enh_p,
                                                   const __hip_bfloat16* __restrict__ enl_p,
                                                   const __hip_bfloat16* __restrict__ pnh_p,
                                                   const __hip_bfloat16* __restrict__ pnl_p,
                                                   float* __restrict__ sim,
                                                   float* __restrict__ cosm) {
    extern __shared__ char smem[];
    char* As = smem;           // 64 rows * 512B: kbyte 0..255 = hi, 256..511 = lo
    char* Bs = smem + 32768;
    const int tid = threadIdx.x;
    const __hip_bfloat16* Ah;
    const __hip_bfloat16* Al;
    float* Out;
    int rb;
    if (blockIdx.y < 32) { Ah = enh_p; Al = enl_p; Out = sim;  rb = blockIdx.y << 6; }
    else                 { Ah = pnh_p; Al = pnl_p; Out = cosm; rb = (blockIdx.y - 32) << 6; }
    const int cb = blockIdx.x << 6;
    {
        int r = tid >> 2;
        int c0 = (tid & 3) << 5;
        int sw = (r & 7) << 4;
#pragma unroll
        for (int j = 0; j < 4; ++j) {
            int c = c0 + (j << 3);
            uint4 vh = *(const uint4*)&Ah[(rb + r) * D_SZ + c];
            *(uint4*)(As + r * 512 + ((2 * c) ^ sw)) = vh;
            uint4 vl = *(const uint4*)&Al[(rb + r) * D_SZ + c];
            *(uint4*)(As + r * 512 + ((512 + 2 * c) ^ sw) - 256) = vl;
            uint4 wh = *(const uint4*)&enh_p[(cb + r) * D_SZ + c];
            *(uint4*)(Bs + r * 512 + ((2 * c) ^ sw)) = wh;
            uint4 wl = *(const uint4*)&enl_p[(cb + r) * D_SZ + c];
            *(uint4*)(Bs + r * 512 + ((512 + 2 * c) ^ sw) - 256) = wl;
        }
    }
    __syncthreads();
    const int w = tid >> 6, lane = tid & 63;
    const int wr = (w >> 1) << 5;
    const int wc = (w & 1) << 5;
    const int lrow = lane & 15;
    const int lk = (lane >> 4) << 4;
    int ar0 = wr + lrow, ar1 = wr + 16 + lrow;
    int br0 = wc + lrow, br1 = wc + 16 + lrow;
    const char* pa0 = As + ar0 * 512; const int swa0 = (ar0 & 7) << 4;
    const char* pa1 = As + ar1 * 512; const int swa1 = (ar1 & 7) << 4;
    const char* pb0 = Bs + br0 * 512; const int swb0 = (br0 & 7) << 4;
    const char* pb1 = Bs + br1 * 512; const int swb1 = (br1 & 7) << 4;
    f32x4 acc00 = {0.f, 0.f, 0.f, 0.f};
    f32x4 acc01 = acc00, acc10 = acc00, acc11 = acc00;
#pragma unroll
    for (int term = 0; term < 3; ++term) {
        const int ao = (term == 2) ? 256 : 0;   // A: hi,hi,lo
        const int bo = (term == 1) ? 256 : 0;   // B: hi,lo,hi
#pragma unroll
        for (int kk = 0; kk < 4; ++kk) {
            const int ka = ao + (kk << 6) + lk;
            const int kb = bo + (kk << 6) + lk;
            short8 a0 = *(const short8*)(pa0 + ((ka & 0x100) | ((ka & 0xFF) ^ swa0)));
            short8 a1 = *(const short8*)(pa1 + ((ka & 0x100) | ((ka & 0xFF) ^ swa1)));
            short8 b0 = *(const short8*)(pb0 + ((kb & 0x100) | ((kb & 0xFF) ^ swb0)));
            short8 b1 = *(const short8*)(pb1 + ((kb & 0x100) | ((kb & 0xFF) ^ swb1)));
            acc00 = __builtin_amdgcn_mfma_f32_16x16x32_bf16(a0, b0, acc00, 0, 0, 0);
            acc01 = __builtin_amdgcn_mfma_f32_16x16x32_bf16(a0, b1, acc01, 0, 0, 0);
            acc10 = __builtin_amdgcn_mfma_f32_16x16x32_bf16(a1, b0, acc10, 0, 0, 0);
            acc11 = __builtin_amdgcn_mfma_f32_16x16x32_bf16(a1, b1, acc11, 0, 0, 0);
        }
    }
    const int crow = rb + wr + ((lane >> 4) << 2);
    const int ccol = cb + wc + lrow;
#pragma unroll
    for (int r = 0; r < 4; ++r) {
        Out[(crow + r) * C_SZ + ccol]           = acc00[r];
        Out[(crow + r) * C_SZ + ccol + 16]      = acc01[r];
        Out[(crow + 16 + r) * C_SZ + ccol]      = acc10[r];
        Out[(crow + 16 + r) * C_SZ + ccol + 16] = acc11[r];
    }
}

// Two rows per 512-thread block; per row: single-pass bucket-rank (packed u16
// hist fields, split key/idx arrays) -> discounted logits -> log_softmax ->
// diagonal -> loss. Two independent chains per phase hide LDS/L3 latency.
__global__ __launch_bounds__(512) void k_rank_softmax(const float* __restrict__ sim,
                                                      const float* __restrict__ cosm,
                                                      const int* __restrict__ pos_count,
                                                      const float* __restrict__ tab,
                                                      float* __restrict__ acc) {
    const int i0 = blockIdx.x << 1;
    __shared__ unsigned s_keys[2][C_SZ];          // 16 KB
    __shared__ unsigned short s_idx[2][C_SZ];     // 8 KB
    __shared__ unsigned s_hist[2][C_SZ / 2];      // 8 KB (2x u16 fields per word)
    __shared__ int s_wt[2][8];
    __shared__ float s_redm[2][8];
    __shared__ float s_reds[2][8];
    __shared__ float s_diag[2];
    const int tid = threadIdx.x;     // 0..511
    const int lane = tid & 63;
    const int w = tid >> 6;          // 0..7
    const int base = tid << 2;       // 4 elems/thread/row

    const bool v0 = pos_count[i0] != 0;
    const bool v1 = pos_count[i0 + 1] != 0;

    // loads for both rows (independent streams)
    float4 sa0 = *(const float4*)&sim[i0 * C_SZ + base];
    float4 sa1 = *(const float4*)&sim[(i0 + 1) * C_SZ + base];
    float4 ca0 = *(const float4*)&cosm[i0 * C_SZ + base];
    float4 ca1 = *(const float4*)&cosm[(i0 + 1) * C_SZ + base];
    // zero packed hists: 2048 words / 512 thr = 4 words = 1 uint4 per thread
    {
        uint4 z4 = {0u, 0u, 0u, 0u};
        ((uint4*)s_hist)[tid] = z4;
    }
    float xs0[4] = {sa0.x, sa0.y, sa0.z, sa0.w};
    float xs1[4] = {sa1.x, sa1.y, sa1.z, sa1.w};
    unsigned uk0[4], uk1[4];
    int bk0[4], bk1[4];
#pragma unroll
    for (int e = 0; e < 4; ++e) {
        unsigned u = __float_as_uint(xs0[e]);
        u = (u & 0x80000000u) ? ~u : (u | 0x80000000u);
        if (u == 0x7FFFFFFFu) u = 0x80000000u;
        uk0[e] = u;
        int b = (int)((xs0[e] + 1.0f) * 1023.5f);
        bk0[e] = b < 0 ? 0 : (b > 2047 ? 2047 : b);
        unsigned u1 = __float_as_uint(xs1[e]);
        u1 = (u1 & 0x80000000u) ? ~u1 : (u1 | 0x80000000u);
        if (u1 == 0x7FFFFFFFu) u1 = 0x80000000u;
        uk1[e] = u1;
        int b1 = (int)((xs1[e] + 1.0f) * 1023.5f);
        bk1[e] = b1 < 0 ? 0 : (b1 > 2047 ? 2047 : b1);
    }
    __syncthreads();
    // histogram (packed 16-bit fields)
    if (v0) {
#pragma unroll
        for (int e = 0; e < 4; ++e)
            atomicAdd(&s_hist[0][bk0[e] >> 1], 1u << ((bk0[e] & 1) << 4));
    }
    if (v1) {
#pragma unroll
        for (int e = 0; e < 4; ++e)
            atomicAdd(&s_hist[1][bk1[e] >> 1], 1u << ((bk1[e] & 1) << 4));
    }
    __syncthreads();
    // exclusive scan (4 buckets = 2 words per thread per row)
    unsigned w00 = s_hist[0][2 * tid], w01 = s_hist[0][2 * tid + 1];
    unsigned w10 = s_hist[1][2 * tid], w11 = s_hist[1][2 * tid + 1];
    unsigned c00 = w00 & 0xFFFF, c01 = w00 >> 16, c02 = w01 & 0xFFFF, c03 = w01 >> 16;
    unsigned c10 = w10 & 0xFFFF, c11 = w10 >> 16, c12 = w11 & 0xFFFF, c13 = w11 >> 16;
    unsigned sum0 = c00 + c01 + c02 + c03;
    unsigned sum1 = c10 + c11 + c12 + c13;
    int incl0 = (int)sum0, incl1 = (int)sum1;
#pragma unroll
    for (int off = 1; off < 64; off <<= 1) {
        int o0 = __shfl_up(incl0, off);
        int o1 = __shfl_up(incl1, off);
        if (lane >= off) { incl0 += o0; incl1 += o1; }
    }
    if (lane == 63) { s_wt[0][w] = incl0; s_wt[1][w] = incl1; }
    __syncthreads();
    int wb0 = 0, wb1 = 0;
#pragma unroll
    for (int ww = 0; ww < 8; ++ww) {
        wb0 += (ww < w) ? s_wt[0][ww] : 0;
        wb1 += (ww < w) ? s_wt[1][ww] : 0;
    }
    unsigned eb0 = (unsigned)(wb0 + incl0 - (int)sum0);
    unsigned eb1 = (unsigned)(wb1 + incl1 - (int)sum1);
    {
        unsigned e00 = eb0, e01 = eb0 + c00, e02 = eb0 + c00 + c01, e03 = eb0 + c00 + c01 + c02;
        s_hist[0][2 * tid]     = e00 | (e01 << 16);
        s_hist[0][2 * tid + 1] = e02 | (e03 << 16);
        unsigned e10 = eb1, e11 = eb1 + c10, e12 = eb1 + c10 + c11, e13 = eb1 + c10 + c11 + c12;
        s_hist[1][2 * tid]     = e10 | (e11 << 16);
        s_hist[1][2 * tid + 1] = e12 | (e13 << 16);
    }
    __syncthreads();
    // scatter (key, idx separately; field-packed position counter)
    if (v0) {
#pragma unroll
        for (int e = 0; e < 4; ++e) {
            int sh = (bk0[e] & 1) << 4;
            unsigned old = atomicAdd(&s_hist[0][bk0[e] >> 1], 1u << sh);
            unsigned pos = (old >> sh) & 0xFFFFu;
            s_keys[0][pos] = uk0[e];
            s_idx[0][pos] = (unsigned short)(base + e);
        }
    }
    if (v1) {
#pragma unroll
        for (int e = 0; e < 4; ++e) {
            int sh = (bk1[e] & 1) << 4;
            unsigned old = atomicAdd(&s_hist[1][bk1[e] >> 1], 1u << sh);
            unsigned pos = (old >> sh) & 0xFFFFu;
            s_keys[1][pos] = uk1[e];
            s_idx[1][pos] = (unsigned short)(base + e);
        }
    }
    __syncthreads();
    // rank + logits per row
    float lg0[4], lg1[4];
    float lmax0 = -3.4e38f, lmax1 = -3.4e38f;
    float cs0[4] = {ca0.x, ca0.y, ca0.z, ca0.w};
    float cs1[4] = {ca1.x, ca1.y, ca1.z, ca1.w};
    if (v0) {
#pragma unroll
        for (int e = 0; e < 4; ++e) {
            int b = bk0[e];
            unsigned endv = (s_hist[0][b >> 1] >> ((b & 1) << 4)) & 0xFFFFu;
            unsigned startv = b ? ((s_hist[0][(b - 1) >> 1] >> (((b - 1) & 1) << 4)) & 0xFFFFu) : 0u;
            unsigned mk = uk0[e];
            int less = 0, eq = 0;
            for (unsigned j = startv; j < endv; ++j) {
                unsigned kj = s_keys[0][j];
                less += (kj < mk) ? 1 : 0;
                eq += (kj == mk) ? 1 : 0;
            }
            if (eq > 1) {
                unsigned myi = (unsigned)(base + e);
                for (unsigned j = startv; j < endv; ++j)
                    if (s_keys[0][j] == mk && (unsigned)s_idx[0][j] < myi) less++;
            }
            int rk = (int)startv + less;
            lg0[e] = cs0[e] * tab[rk];
            lmax0 = fmaxf(lmax0, lg0[e]);
        }
        if ((i0 >> 2) == tid) {
            int ei = i0 & 3;
            float dv = lg0[0];
#pragma unroll
            for (int e = 1; e < 4; ++e) dv = (ei == e) ? lg0[e] : dv;
            s_diag[0] = dv;
        }
    }
    if (v1) {
#pragma unroll
        for (int e = 0; e < 4; ++e) {
            int b = bk1[e];
            unsigned endv = (s_hist[1][b >> 1] >> ((b & 1) << 4)) & 0xFFFFu;
            unsigned startv = b ? ((s_hist[1][(b - 1) >> 1] >> (((b - 1) & 1) << 4)) & 0xFFFFu) : 0u;
            unsigned mk = uk1[e];
            int less = 0, eq = 0;
            for (unsigned j = startv; j < endv; ++j) {
                unsigned kj = s_keys[1][j];
                less += (kj < mk) ? 1 : 0;
                eq += (kj == mk) ? 1 : 0;
            }
            if (eq > 1) {
                unsigned myi = (unsigned)(base + e);
                for (unsigned j = startv; j < endv; ++j)
                    if (s_keys[1][j] == mk && (unsigned)s_idx[1][j] < myi) less++;
            }
            int rk = (int)startv + less;
            lg1[e] = cs1[e] * tab[rk];
            lmax1 = fmaxf(lmax1, lg1[e]);
        }
        if (((i0 + 1) >> 2) == tid) {
            int ei = (i0 + 1) & 3;
            float dv = lg1[0];
#pragma unroll
            for (int e = 1; e < 4; ++e) dv = (ei == e) ? lg1[e] : dv;
            s_diag[1] = dv;
        }
    }
#pragma unroll
    for (int off = 1; off < 64; off <<= 1) {
        lmax0 = fmaxf(lmax0, __shfl_xor(lmax0, off));
        lmax1 = fmaxf(lmax1, __shfl_xor(lmax1, off));
    }
    if (lane == 0) { s_redm[0][w] = lmax0; s_redm[1][w] = lmax1; }
    __syncthreads();
    float m0 = s_redm[0][0], m1 = s_redm[1][0];
#pragma unroll
    for (int ww = 1; ww < 8; ++ww) {
        m0 = fmaxf(m0, s_redm[0][ww]);
        m1 = fmaxf(m1, s_redm[1][ww]);
    }
    float ls0 = 0.f, ls1 = 0.f;
    if (v0) {
#pragma unroll
        for (int e = 0; e < 4; ++e) ls0 += __expf(lg0[e] - m0);
    }
    if (v1) {
#pragma unroll
        for (int e = 0; e < 4; ++e) ls1 += __expf(lg1[e] - m1);
    }
#pragma unroll
    for (int off = 1; off < 64; off <<= 1) {
        ls0 += __shfl_xor(ls0, off);
        ls1 += __shfl_xor(ls1, off);
    }
    if (lane == 0) { s_reds[0][w] = ls0; s_reds[1][w] = ls1; }
    __syncthreads();
    if (tid == 0) {
        float t0 = 0.f, t1 = 0.f;
#pragma unroll
        for (int ww = 0; ww < 8; ++ww) { t0 += s_reds[0][ww]; t1 += s_reds[1][ww]; }
        float lp = 0.f, nv = 0.f;
        if (v0) { lp += -(s_diag[0] - m0 - logf(t0)); nv += 1.f; }
        if (v1) { lp += -(s_diag[1] - m1 - logf(t1)); nv += 1.f; }
        if (nv > 0.f) {
            atomicAdd(&acc[0], lp);
            atomicAdd(&acc[1], nv);
        }
    }
}

__global__ void k_final(const float* __restrict__ acc, float* __restrict__ out) {
    out[0] = acc[0] / fmaxf(acc[1], 1.0f);
}

extern "C" void kernel_launch(void* const* d_in, const int* in_sizes, int n_in,
                              void* d_out, int out_size, void* d_ws, size_t ws_size,
                              hipStream_t stream) {
    const float* output    = (const float*)d_in[0];
    const float* class_emb = (const float*)d_in[1];
    const float* targets   = (const float*)d_in[2];
    const float* tempPtr   = (const float*)d_in[3];
    float* out = (float*)d_out;
    char* ws = (char*)d_ws;

    int*   pos_count = (int*)(ws + 0);
    float* acc       = (float*)(ws + 8192);
    int*   pos_list  = (int*)(ws + 8448);
    __hip_bfloat16* pnh = (__hip_bfloat16*)(ws + 2105600);
    __hip_bfloat16* pnl = (__hip_bfloat16*)(ws + 2629888);
    __hip_bfloat16* enh = (__hip_bfloat16*)(ws + 3154176);
    __hip_bfloat16* enl = (__hip_bfloat16*)(ws + 3678464);
    float* tab       = (float*)(ws + 4202752);
    float* sim       = (float*)(ws + 4210944);
    float* cosm      = (float*)(ws + 20988160);

    k_pre<<<C_SZ + 17, 128, 0, stream>>>(class_emb, tempPtr, enh, enl, tab, (unsigned*)ws);
    k_scan<<<4096, 256, 0, stream>>>(targets, pos_count, pos_list);
    k_pool<<<C_SZ, 128, 0, stream>>>(output, pos_count, pos_list, pnh, pnl);
    dim3 g(C_SZ / 64, 2 * C_SZ / 64);
    k_gemm_mfma<<<g, 256, 65536, stream>>>(enh, enl, pnh, pnl, sim, cosm);
    k_rank_softmax<<<C_SZ / 2, 512, 0, stream>>>(sim, cosm, pos_count, tab, acc);
    k_final<<<1, 1, 0, stream>>>(acc, out);
}

// Round 9
// 107.174 us; speedup vs baseline: 1.5038x; 1.0438x over previous
//
#include <hip/hip_runtime.h>
#include <hip/hip_bf16.h>
#include <math.h>

#define B_SZ 16384
#define C_SZ 2048
#define D_SZ 128
#define MAXP 256
#define SCAN_BLOCKS 4096

typedef float f32x4 __attribute__((ext_vector_type(4)));
typedef short short8 __attribute__((ext_vector_type(8)));

// ---- workspace layout (bytes) ----
// 0        : pos_count[C]     int   (8192)
// 8192     : acc[2]           float (8)
// 8448     : pos_list[C*MAXP] int   (2 MB)   -> 2,105,600
// 2105600  : pnh [C*D] bf16 (512KB) -> 2,629,888
// 2629888  : pnl [C*D] bf16 (512KB) -> 3,154,176
// 3154176  : enh [C*D] bf16 (512KB) -> 3,678,464
// 3678464  : enl [C*D] bf16 (512KB) -> 4,202,752
// 4202752  : tab[C] f32 (8KB)       -> 4,210,944
// 4210944  : sim[C*C] f32 (16MB)    -> 20,988,160
// 20988160 : cosm[C*C] f32 (16MB)   -> 37,765,376

// zero pos_count/acc only (tiny)
__global__ __launch_bounds__(256) void k_pre(unsigned* __restrict__ zr) {
    int t = blockIdx.x * blockDim.x + threadIdx.x;
    if (t < 2112) zr[t] = 0u;
}

// blocks 0..4095: scan targets -> pos lists.  blocks 4096+: L2-normalize
// class_emb (2 classes per 256-thr block) + tab. Norm work hides under the
// HBM-bound targets read.
__global__ __launch_bounds__(256) void k_scan(const float* __restrict__ targets,
                                              const float* __restrict__ class_emb,
                                              const float* __restrict__ tempPtr,
                                              int* __restrict__ pos_count,
                                              int* __restrict__ pos_list,
                                              __hip_bfloat16* __restrict__ enh,
                                              __hip_bfloat16* __restrict__ enl,
                                              float* __restrict__ tab) {
    const int bid = blockIdx.x;
    if (bid >= SCAN_BLOCKS) {
        const int g = threadIdx.x >> 7;        // 0..1 class within block
        const int d = threadIdx.x & 127;
        const int c = ((bid - SCAN_BLOCKS) << 1) + g;
        __shared__ float s_w[2][2];
        float v = class_emb[c * D_SZ + d];
        float sq = v * v;
#pragma unroll
        for (int off = 32; off >= 1; off >>= 1) sq += __shfl_xor(sq, off);
        if ((d & 63) == 0) s_w[g][d >> 6] = sq;
        __syncthreads();
        float tot = s_w[g][0] + s_w[g][1];
        float vn = v * rsqrtf(tot + 1e-12f);
        __hip_bfloat16 h = __float2bfloat16(vn);
        enh[c * D_SZ + d] = h;
        enl[c * D_SZ + d] = __float2bfloat16(vn - __bfloat162float(h));
        if (d == 0) tab[c] = 1.0f / (tempPtr[0] * logf((float)c + 2.0f));
        return;
    }
    int tid = bid * 256 + threadIdx.x;
    int total = (B_SZ * C_SZ) >> 2;
    const int stride = SCAN_BLOCKS * 256;
    for (int v = tid; v < total; v += stride) {
        float4 t = ((const float4*)targets)[v];
        if (t.x != 0.f || t.y != 0.f || t.z != 0.f || t.w != 0.f) {
            int e0 = v << 2;
            int b = e0 >> 11;
            int c0 = e0 & (C_SZ - 1);
            float vals[4] = {t.x, t.y, t.z, t.w};
#pragma unroll
            for (int q = 0; q < 4; ++q) {
                if (vals[q] != 0.f) {
                    int c = c0 + q;
                    int slot = atomicAdd(&pos_count[c], 1);
                    if (slot < MAXP) pos_list[c * MAXP + slot] = b;
                }
            }
        }
    }
}

// masked mean pool + L2 norm -> pn(h,l)
__global__ __launch_bounds__(128) void k_pool(const float* __restrict__ output,
                                              const int* __restrict__ pos_count,
                                              const int* __restrict__ pos_list,
                                              __hip_bfloat16* __restrict__ pnh,
                                              __hip_bfloat16* __restrict__ pnl) {
    int c = blockIdx.x;
    int d = threadIdx.x;
    __shared__ float s_w[2];
    int n = pos_count[c];
    if (n > MAXP) n = MAXP;
    float acc = 0.f, cnt = 0.f;
    for (int k = 0; k < n; ++k) {
        int b = pos_list[c * MAXP + k];
        float v = output[b * D_SZ + d];
        acc += v;
        cnt += (v != 0.f) ? 1.f : 0.f;
    }
    float pooled = acc / (cnt + 1e-9f);
    float sq = pooled * pooled;
#pragma unroll
    for (int off = 32; off >= 1; off >>= 1) sq += __shfl_xor(sq, off);
    if ((d & 63) == 0) s_w[d >> 6] = sq;
    __syncthreads();
    float tot = s_w[0] + s_w[1];
    float vn = pooled * rsqrtf(tot + 1e-12f);
    __hip_bfloat16 h = __float2bfloat16(vn);
    pnh[c * D_SZ + d] = h;
    pnl[c * D_SZ + d] = __float2bfloat16(vn - __bfloat162float(h));
}

// Fused: rows 0..2047 = en @ en^T -> sim ; rows 2048..4095 = pn @ en^T -> cosm.
__global__ __launch_bounds__(256) void k_gemm_mfma(const __hip_bfloat16* __restrict__ enh_p,
                                                   const __hip_bfloat16* __restrict__ enl_p,
                                                   const __hip_bfloat16* __restrict__ pnh_p,
                                                   const __hip_bfloat16* __restrict__ pnl_p,
                                                   float* __restrict__ sim,
                                                   float* __restrict__ cosm) {
    extern __shared__ char smem[];
    char* As = smem;           // 64 rows * 512B: kbyte 0..255 = hi, 256..511 = lo
    char* Bs = smem + 32768;
    const int tid = threadIdx.x;
    const __hip_bfloat16* Ah;
    const __hip_bfloat16* Al;
    float* Out;
    int rb;
    if (blockIdx.y < 32) { Ah = enh_p; Al = enl_p; Out = sim;  rb = blockIdx.y << 6; }
    else                 { Ah = pnh_p; Al = pnl_p; Out = cosm; rb = (blockIdx.y - 32) << 6; }
    const int cb = blockIdx.x << 6;
    {
        int r = tid >> 2;
        int c0 = (tid & 3) << 5;
        int sw = (r & 7) << 4;
#pragma unroll
        for (int j = 0; j < 4; ++j) {
            int c = c0 + (j << 3);
            uint4 vh = *(const uint4*)&Ah[(rb + r) * D_SZ + c];
            *(uint4*)(As + r * 512 + ((2 * c) ^ sw)) = vh;
            uint4 vl = *(const uint4*)&Al[(rb + r) * D_SZ + c];
            *(uint4*)(As + r * 512 + ((512 + 2 * c) ^ sw) - 256) = vl;
            uint4 wh = *(const uint4*)&enh_p[(cb + r) * D_SZ + c];
            *(uint4*)(Bs + r * 512 + ((2 * c) ^ sw)) = wh;
            uint4 wl = *(const uint4*)&enl_p[(cb + r) * D_SZ + c];
            *(uint4*)(Bs + r * 512 + ((512 + 2 * c) ^ sw) - 256) = wl;
        }
    }
    __syncthreads();
    const int w = tid >> 6, lane = tid & 63;
    const int wr = (w >> 1) << 5;
    const int wc = (w & 1) << 5;
    const int lrow = lane & 15;
    const int lk = (lane >> 4) << 4;
    int ar0 = wr + lrow, ar1 = wr + 16 + lrow;
    int br0 = wc + lrow, br1 = wc + 16 + lrow;
    const char* pa0 = As + ar0 * 512; const int swa0 = (ar0 & 7) << 4;
    const char* pa1 = As + ar1 * 512; const int swa1 = (ar1 & 7) << 4;
    const char* pb0 = Bs + br0 * 512; const int swb0 = (br0 & 7) << 4;
    const char* pb1 = Bs + br1 * 512; const int swb1 = (br1 & 7) << 4;
    f32x4 acc00 = {0.f, 0.f, 0.f, 0.f};
    f32x4 acc01 = acc00, acc10 = acc00, acc11 = acc00;
#pragma unroll
    for (int term = 0; term < 3; ++term) {
        const int ao = (term == 2) ? 256 : 0;   // A: hi,hi,lo
        const int bo = (term == 1) ? 256 : 0;   // B: hi,lo,hi
#pragma unroll
        for (int kk = 0; kk < 4; ++kk) {
            const int ka = ao + (kk << 6) + lk;
            const int kb = bo + (kk << 6) + lk;
            short8 a0 = *(const short8*)(pa0 + ((ka & 0x100) | ((ka & 0xFF) ^ swa0)));
            short8 a1 = *(const short8*)(pa1 + ((ka & 0x100) | ((ka & 0xFF) ^ swa1)));
            short8 b0 = *(const short8*)(pb0 + ((kb & 0x100) | ((kb & 0xFF) ^ swb0)));
            short8 b1 = *(const short8*)(pb1 + ((kb & 0x100) | ((kb & 0xFF) ^ swb1)));
            acc00 = __builtin_amdgcn_mfma_f32_16x16x32_bf16(a0, b0, acc00, 0, 0, 0);
            acc01 = __builtin_amdgcn_mfma_f32_16x16x32_bf16(a0, b1, acc01, 0, 0, 0);
            acc10 = __builtin_amdgcn_mfma_f32_16x16x32_bf16(a1, b0, acc10, 0, 0, 0);
            acc11 = __builtin_amdgcn_mfma_f32_16x16x32_bf16(a1, b1, acc11, 0, 0, 0);
        }
    }
    const int crow = rb + wr + ((lane >> 4) << 2);
    const int ccol = cb + wc + lrow;
#pragma unroll
    for (int r = 0; r < 4; ++r) {
        Out[(crow + r) * C_SZ + ccol]           = acc00[r];
        Out[(crow + r) * C_SZ + ccol + 16]      = acc01[r];
        Out[(crow + 16 + r) * C_SZ + ccol]      = acc10[r];
        Out[(crow + 16 + r) * C_SZ + ccol + 16] = acc11[r];
    }
}

// Two rows per 512-thread block. Bucket map tightened to [-0.5,0.5] (sims are
// ~N(0,1/128) off-diagonal; clamp buckets stay exact via compare loop). Fixed
// softmax shift M=21 (|logit| <= 1.01/(0.07*ln2) < 21) removes the max phase.
__global__ __launch_bounds__(512) void k_rank_softmax(const float* __restrict__ sim,
                                                      const float* __restrict__ cosm,
                                                      const int* __restrict__ pos_count,
                                                      const float* __restrict__ tab,
                                                      float* __restrict__ acc) {
    const int i0 = blockIdx.x << 1;
    __shared__ unsigned s_keys[2][C_SZ];          // 16 KB
    __shared__ unsigned short s_idx[2][C_SZ];     // 8 KB
    __shared__ unsigned s_hist[2][C_SZ / 2];      // 8 KB (2x u16 fields per word)
    __shared__ int s_wt[2][8];
    __shared__ float s_reds[2][8];
    __shared__ float s_diag[2];
    const int tid = threadIdx.x;     // 0..511
    const int lane = tid & 63;
    const int w = tid >> 6;          // 0..7
    const int base = tid << 2;       // 4 elems/thread/row
    const float M = 21.0f;

    const bool v0 = pos_count[i0] != 0;
    const bool v1 = pos_count[i0 + 1] != 0;

    float4 sa0 = *(const float4*)&sim[i0 * C_SZ + base];
    float4 sa1 = *(const float4*)&sim[(i0 + 1) * C_SZ + base];
    float4 ca0 = *(const float4*)&cosm[i0 * C_SZ + base];
    float4 ca1 = *(const float4*)&cosm[(i0 + 1) * C_SZ + base];
    {
        uint4 z4 = {0u, 0u, 0u, 0u};
        ((uint4*)s_hist)[tid] = z4;
    }
    float xs0[4] = {sa0.x, sa0.y, sa0.z, sa0.w};
    float xs1[4] = {sa1.x, sa1.y, sa1.z, sa1.w};
    unsigned uk0[4], uk1[4];
    int bk0[4], bk1[4];
#pragma unroll
    for (int e = 0; e < 4; ++e) {
        unsigned u = __float_as_uint(xs0[e]);
        u = (u & 0x80000000u) ? ~u : (u | 0x80000000u);
        if (u == 0x7FFFFFFFu) u = 0x80000000u;
        uk0[e] = u;
        int b = (int)((xs0[e] + 0.5f) * 2047.0f);
        bk0[e] = b < 0 ? 0 : (b > 2047 ? 2047 : b);
        unsigned u1 = __float_as_uint(xs1[e]);
        u1 = (u1 & 0x80000000u) ? ~u1 : (u1 | 0x80000000u);
        if (u1 == 0x7FFFFFFFu) u1 = 0x80000000u;
        uk1[e] = u1;
        int b1 = (int)((xs1[e] + 0.5f) * 2047.0f);
        bk1[e] = b1 < 0 ? 0 : (b1 > 2047 ? 2047 : b1);
    }
    __syncthreads();
    if (v0) {
#pragma unroll
        for (int e = 0; e < 4; ++e)
            atomicAdd(&s_hist[0][bk0[e] >> 1], 1u << ((bk0[e] & 1) << 4));
    }
    if (v1) {
#pragma unroll
        for (int e = 0; e < 4; ++e)
            atomicAdd(&s_hist[1][bk1[e] >> 1], 1u << ((bk1[e] & 1) << 4));
    }
    __syncthreads();
    unsigned w00 = s_hist[0][2 * tid], w01 = s_hist[0][2 * tid + 1];
    unsigned w10 = s_hist[1][2 * tid], w11 = s_hist[1][2 * tid + 1];
    unsigned c00 = w00 & 0xFFFF, c01 = w00 >> 16, c02 = w01 & 0xFFFF, c03 = w01 >> 16;
    unsigned c10 = w10 & 0xFFFF, c11 = w10 >> 16, c12 = w11 & 0xFFFF, c13 = w11 >> 16;
    unsigned sum0 = c00 + c01 + c02 + c03;
    unsigned sum1 = c10 + c11 + c12 + c13;
    int incl0 = (int)sum0, incl1 = (int)sum1;
#pragma unroll
    for (int off = 1; off < 64; off <<= 1) {
        int o0 = __shfl_up(incl0, off);
        int o1 = __shfl_up(incl1, off);
        if (lane >= off) { incl0 += o0; incl1 += o1; }
    }
    if (lane == 63) { s_wt[0][w] = incl0; s_wt[1][w] = incl1; }
    __syncthreads();
    int wb0 = 0, wb1 = 0;
#pragma unroll
    for (int ww = 0; ww < 8; ++ww) {
        wb0 += (ww < w) ? s_wt[0][ww] : 0;
        wb1 += (ww < w) ? s_wt[1][ww] : 0;
    }
    unsigned eb0 = (unsigned)(wb0 + incl0 - (int)sum0);
    unsigned eb1 = (unsigned)(wb1 + incl1 - (int)sum1);
    {
        unsigned e00 = eb0, e01 = eb0 + c00, e02 = eb0 + c00 + c01, e03 = eb0 + c00 + c01 + c02;
        s_hist[0][2 * tid]     = e00 | (e01 << 16);
        s_hist[0][2 * tid + 1] = e02 | (e03 << 16);
        unsigned e10 = eb1, e11 = eb1 + c10, e12 = eb1 + c10 + c11, e13 = eb1 + c10 + c11 + c12;
        s_hist[1][2 * tid]     = e10 | (e11 << 16);
        s_hist[1][2 * tid + 1] = e12 | (e13 << 16);
    }
    __syncthreads();
    if (v0) {
#pragma unroll
        for (int e = 0; e < 4; ++e) {
            int sh = (bk0[e] & 1) << 4;
            unsigned old = atomicAdd(&s_hist[0][bk0[e] >> 1], 1u << sh);
            unsigned pos = (old >> sh) & 0xFFFFu;
            s_keys[0][pos] = uk0[e];
            s_idx[0][pos] = (unsigned short)(base + e);
        }
    }
    if (v1) {
#pragma unroll
        for (int e = 0; e < 4; ++e) {
            int sh = (bk1[e] & 1) << 4;
            unsigned old = atomicAdd(&s_hist[1][bk1[e] >> 1], 1u << sh);
            unsigned pos = (old >> sh) & 0xFFFFu;
            s_keys[1][pos] = uk1[e];
            s_idx[1][pos] = (unsigned short)(base + e);
        }
    }
    __syncthreads();
    // rank + logits + partial expsum (fixed shift M)
    float ls0 = 0.f, ls1 = 0.f;
    float cs0[4] = {ca0.x, ca0.y, ca0.z, ca0.w};
    float cs1[4] = {ca1.x, ca1.y, ca1.z, ca1.w};
    if (v0) {
        float lg0[4];
#pragma unroll
        for (int e = 0; e < 4; ++e) {
            int b = bk0[e];
            unsigned endv = (s_hist[0][b >> 1] >> ((b & 1) << 4)) & 0xFFFFu;
            unsigned startv = b ? ((s_hist[0][(b - 1) >> 1] >> (((b - 1) & 1) << 4)) & 0xFFFFu) : 0u;
            unsigned mk = uk0[e];
            int less = 0, eq = 0;
            for (unsigned j = startv; j < endv; ++j) {
                unsigned kj = s_keys[0][j];
                less += (kj < mk) ? 1 : 0;
                eq += (kj == mk) ? 1 : 0;
            }
            if (eq > 1) {
                unsigned myi = (unsigned)(base + e);
                for (unsigned j = startv; j < endv; ++j)
                    if (s_keys[0][j] == mk && (unsigned)s_idx[0][j] < myi) less++;
            }
            int rk = (int)startv + less;
            lg0[e] = cs0[e] * tab[rk];
            ls0 += __expf(lg0[e] - M);
        }
        if ((i0 >> 2) == tid) {
            int ei = i0 & 3;
            float dv = lg0[0];
#pragma unroll
            for (int e = 1; e < 4; ++e) dv = (ei == e) ? lg0[e] : dv;
            s_diag[0] = dv;
        }
    }
    if (v1) {
        float lg1[4];
#pragma unroll
        for (int e = 0; e < 4; ++e) {
            int b = bk1[e];
            unsigned endv = (s_hist[1][b >> 1] >> ((b & 1) << 4)) & 0xFFFFu;
            unsigned startv = b ? ((s_hist[1][(b - 1) >> 1] >> (((b - 1) & 1) << 4)) & 0xFFFFu) : 0u;
            unsigned mk = uk1[e];
            int less = 0, eq = 0;
            for (unsigned j = startv; j < endv; ++j) {
                unsigned kj = s_keys[1][j];
                less += (kj < mk) ? 1 : 0;
                eq += (kj == mk) ? 1 : 0;
            }
            if (eq > 1) {
                unsigned myi = (unsigned)(base + e);
                for (unsigned j = startv; j < endv; ++j)
                    if (s_keys[1][j] == mk && (unsigned)s_idx[1][j] < myi) less++;
            }
            int rk = (int)startv + less;
            lg1[e] = cs1[e] * tab[rk];
            ls1 += __expf(lg1[e] - M);
        }
        if (((i0 + 1) >> 2) == tid) {
            int ei = (i0 + 1) & 3;
            float dv = lg1[0];
#pragma unroll
            for (int e = 1; e < 4; ++e) dv = (ei == e) ? lg1[e] : dv;
            s_diag[1] = dv;
        }
    }
#pragma unroll
    for (int off = 1; off < 64; off <<= 1) {
        ls0 += __shfl_xor(ls0, off);
        ls1 += __shfl_xor(ls1, off);
    }
    if (lane == 0) { s_reds[0][w] = ls0; s_reds[1][w] = ls1; }
    __syncthreads();
    if (tid == 0) {
        float t0 = 0.f, t1 = 0.f;
#pragma unroll
        for (int ww = 0; ww < 8; ++ww) { t0 += s_reds[0][ww]; t1 += s_reds[1][ww]; }
        float lp = 0.f, nv = 0.f;
        if (v0) { lp += -(s_diag[0] - M - logf(t0)); nv += 1.f; }
        if (v1) { lp += -(s_diag[1] - M - logf(t1)); nv += 1.f; }
        if (nv > 0.f) {
            atomicAdd(&acc[0], lp);
            atomicAdd(&acc[1], nv);
        }
    }
}

__global__ void k_final(const float* __restrict__ acc, float* __restrict__ out) {
    out[0] = acc[0] / fmaxf(acc[1], 1.0f);
}

extern "C" void kernel_launch(void* const* d_in, const int* in_sizes, int n_in,
                              void* d_out, int out_size, void* d_ws, size_t ws_size,
                              hipStream_t stream) {
    const float* output    = (const float*)d_in[0];
    const float* class_emb = (const float*)d_in[1];
    const float* targets   = (const float*)d_in[2];
    const float* tempPtr   = (const float*)d_in[3];
    float* out = (float*)d_out;
    char* ws = (char*)d_ws;

    int*   pos_count = (int*)(ws + 0);
    float* acc       = (float*)(ws + 8192);
    int*   pos_list  = (int*)(ws + 8448);
    __hip_bfloat16* pnh = (__hip_bfloat16*)(ws + 2105600);
    __hip_bfloat16* pnl = (__hip_bfloat16*)(ws + 2629888);
    __hip_bfloat16* enh = (__hip_bfloat16*)(ws + 3154176);
    __hip_bfloat16* enl = (__hip_bfloat16*)(ws + 3678464);
    float* tab       = (float*)(ws + 4202752);
    float* sim       = (float*)(ws + 4210944);
    float* cosm      = (float*)(ws + 20988160);

    k_pre<<<9, 256, 0, stream>>>((unsigned*)ws);
    k_scan<<<SCAN_BLOCKS + C_SZ / 2, 256, 0, stream>>>(targets, class_emb, tempPtr,
                                                       pos_count, pos_list, enh, enl, tab);
    k_pool<<<C_SZ, 128, 0, stream>>>(output, pos_count, pos_list, pnh, pnl);
    dim3 g(C_SZ / 64, 2 * C_SZ / 64);
    k_gemm_mfma<<<g, 256, 65536, stream>>>(enh, enl, pnh, pnl, sim, cosm);
    k_rank_softmax<<<C_SZ / 2, 512, 0, stream>>>(sim, cosm, pos_count, tab, acc);
    k_final<<<1, 1, 0, stream>>>(acc, out);
}

// Round 10
// 105.001 us; speedup vs baseline: 1.5349x; 1.0207x over previous
//
#include <hip/hip_runtime.h>
#include <hip/hip_bf16.h>
#include <math.h>

#define B_SZ 16384
#define C_SZ 2048
#define D_SZ 128
#define MAXP 256
#define SCAN_BLOCKS 4096

typedef float f32x4 __attribute__((ext_vector_type(4)));
typedef short short8 __attribute__((ext_vector_type(8)));

// ---- workspace layout (bytes) ----
// 0        : pos_count[C]     int   (8192)
// 8192     : acc[2]           float (8)
// 8448     : pos_list[C*MAXP] int   (2 MB)   -> 2,105,600
// 2105600  : pnh [C*D] bf16 (512KB) -> 2,629,888
// 2629888  : pnl [C*D] bf16 (512KB) -> 3,154,176
// 3154176  : enh [C*D] bf16 (512KB) -> 3,678,464
// 3678464  : enl [C*D] bf16 (512KB) -> 4,202,752
// 4210944  : sim[C*C] f32 (16MB)    -> 20,988,160
// 20988160 : cosm[C*C] f32 (16MB)   -> 37,765,376

// zero pos_count/acc only (tiny)
__global__ __launch_bounds__(256) void k_pre(unsigned* __restrict__ zr) {
    int t = blockIdx.x * blockDim.x + threadIdx.x;
    if (t < 2112) zr[t] = 0u;
}

// blocks 0..4095: scan targets -> pos lists.  blocks 4096+: L2-normalize
// class_emb (2 classes per 256-thr block). Norm hides under HBM-bound scan.
__global__ __launch_bounds__(256) void k_scan(const float* __restrict__ targets,
                                              const float* __restrict__ class_emb,
                                              int* __restrict__ pos_count,
                                              int* __restrict__ pos_list,
                                              __hip_bfloat16* __restrict__ enh,
                                              __hip_bfloat16* __restrict__ enl) {
    const int bid = blockIdx.x;
    if (bid >= SCAN_BLOCKS) {
        const int g = threadIdx.x >> 7;        // 0..1 class within block
        const int d = threadIdx.x & 127;
        const int c = ((bid - SCAN_BLOCKS) << 1) + g;
        __shared__ float s_w[2][2];
        float v = class_emb[c * D_SZ + d];
        float sq = v * v;
#pragma unroll
        for (int off = 32; off >= 1; off >>= 1) sq += __shfl_xor(sq, off);
        if ((d & 63) == 0) s_w[g][d >> 6] = sq;
        __syncthreads();
        float tot = s_w[g][0] + s_w[g][1];
        float vn = v * rsqrtf(tot + 1e-12f);
        __hip_bfloat16 h = __float2bfloat16(vn);
        enh[c * D_SZ + d] = h;
        enl[c * D_SZ + d] = __float2bfloat16(vn - __bfloat162float(h));
        return;
    }
    int tid = bid * 256 + threadIdx.x;
    int total = (B_SZ * C_SZ) >> 2;
    const int stride = SCAN_BLOCKS * 256;
    for (int v = tid; v < total; v += stride) {
        float4 t = ((const float4*)targets)[v];
        if (t.x != 0.f || t.y != 0.f || t.z != 0.f || t.w != 0.f) {
            int e0 = v << 2;
            int b = e0 >> 11;
            int c0 = e0 & (C_SZ - 1);
            float vals[4] = {t.x, t.y, t.z, t.w};
#pragma unroll
            for (int q = 0; q < 4; ++q) {
                if (vals[q] != 0.f) {
                    int c = c0 + q;
                    int slot = atomicAdd(&pos_count[c], 1);
                    if (slot < MAXP) pos_list[c * MAXP + slot] = b;
                }
            }
        }
    }
}

// masked mean pool + L2 norm -> pn(h,l). 256 thr/class: k-loop split in two
// halves (halves the serial gather chain), combined via LDS.
__global__ __launch_bounds__(256) void k_pool(const float* __restrict__ output,
                                              const int* __restrict__ pos_count,
                                              const int* __restrict__ pos_list,
                                              __hip_bfloat16* __restrict__ pnh,
                                              __hip_bfloat16* __restrict__ pnl) {
    int c = blockIdx.x;
    int d = threadIdx.x & 127;
    int half = threadIdx.x >> 7;
    __shared__ float s_acc[2][128];
    __shared__ float s_cnt[2][128];
    __shared__ float s_w[2];
    int n = pos_count[c];
    if (n > MAXP) n = MAXP;
    float acc = 0.f, cnt = 0.f;
    for (int k = half; k < n; k += 2) {
        int b = pos_list[c * MAXP + k];
        float v = output[b * D_SZ + d];
        acc += v;
        cnt += (v != 0.f) ? 1.f : 0.f;
    }
    s_acc[half][d] = acc;
    s_cnt[half][d] = cnt;
    __syncthreads();
    if (half == 0) {
        acc = s_acc[0][d] + s_acc[1][d];
        cnt = s_cnt[0][d] + s_cnt[1][d];
        float pooled = acc / (cnt + 1e-9f);
        float sq = pooled * pooled;
#pragma unroll
        for (int off = 32; off >= 1; off >>= 1) sq += __shfl_xor(sq, off);
        if ((d & 63) == 0) s_w[d >> 6] = sq;
        __syncthreads();
        float tot = s_w[0] + s_w[1];
        float vn = pooled * rsqrtf(tot + 1e-12f);
        __hip_bfloat16 h = __float2bfloat16(vn);
        pnh[c * D_SZ + d] = h;
        pnl[c * D_SZ + d] = __float2bfloat16(vn - __bfloat162float(h));
    } else {
        __syncthreads();   // matching barrier
    }
}

// Fused: rows 0..2047 = en @ en^T -> sim ; rows 2048..4095 = pn @ en^T -> cosm.
__global__ __launch_bounds__(256) void k_gemm_mfma(const __hip_bfloat16* __restrict__ enh_p,
                                                   const __hip_bfloat16* __restrict__ enl_p,
                                                   const __hip_bfloat16* __restrict__ pnh_p,
                                                   const __hip_bfloat16* __restrict__ pnl_p,
                                                   float* __restrict__ sim,
                                                   float* __restrict__ cosm) {
    extern __shared__ char smem[];
    char* As = smem;           // 64 rows * 512B: kbyte 0..255 = hi, 256..511 = lo
    char* Bs = smem + 32768;
    const int tid = threadIdx.x;
    const __hip_bfloat16* Ah;
    const __hip_bfloat16* Al;
    float* Out;
    int rb;
    if (blockIdx.y < 32) { Ah = enh_p; Al = enl_p; Out = sim;  rb = blockIdx.y << 6; }
    else                 { Ah = pnh_p; Al = pnl_p; Out = cosm; rb = (blockIdx.y - 32) << 6; }
    const int cb = blockIdx.x << 6;
    {
        int r = tid >> 2;
        int c0 = (tid & 3) << 5;
        int sw = (r & 7) << 4;
#pragma unroll
        for (int j = 0; j < 4; ++j) {
            int c = c0 + (j << 3);
            uint4 vh = *(const uint4*)&Ah[(rb + r) * D_SZ + c];
            *(uint4*)(As + r * 512 + ((2 * c) ^ sw)) = vh;
            uint4 vl = *(const uint4*)&Al[(rb + r) * D_SZ + c];
            *(uint4*)(As + r * 512 + ((512 + 2 * c) ^ sw) - 256) = vl;
            uint4 wh = *(const uint4*)&enh_p[(cb + r) * D_SZ + c];
            *(uint4*)(Bs + r * 512 + ((2 * c) ^ sw)) = wh;
            uint4 wl = *(const uint4*)&enl_p[(cb + r) * D_SZ + c];
            *(uint4*)(Bs + r * 512 + ((512 + 2 * c) ^ sw) - 256) = wl;
        }
    }
    __syncthreads();
    const int w = tid >> 6, lane = tid & 63;
    const int wr = (w >> 1) << 5;
    const int wc = (w & 1) << 5;
    const int lrow = lane & 15;
    const int lk = (lane >> 4) << 4;
    int ar0 = wr + lrow, ar1 = wr + 16 + lrow;
    int br0 = wc + lrow, br1 = wc + 16 + lrow;
    const char* pa0 = As + ar0 * 512; const int swa0 = (ar0 & 7) << 4;
    const char* pa1 = As + ar1 * 512; const int swa1 = (ar1 & 7) << 4;
    const char* pb0 = Bs + br0 * 512; const int swb0 = (br0 & 7) << 4;
    const char* pb1 = Bs + br1 * 512; const int swb1 = (br1 & 7) << 4;
    f32x4 acc00 = {0.f, 0.f, 0.f, 0.f};
    f32x4 acc01 = acc00, acc10 = acc00, acc11 = acc00;
#pragma unroll
    for (int term = 0; term < 3; ++term) {
        const int ao = (term == 2) ? 256 : 0;   // A: hi,hi,lo
        const int bo = (term == 1) ? 256 : 0;   // B: hi,lo,hi
#pragma unroll
        for (int kk = 0; kk < 4; ++kk) {
            const int ka = ao + (kk << 6) + lk;
            const int kb = bo + (kk << 6) + lk;
            short8 a0 = *(const short8*)(pa0 + ((ka & 0x100) | ((ka & 0xFF) ^ swa0)));
            short8 a1 = *(const short8*)(pa1 + ((ka & 0x100) | ((ka & 0xFF) ^ swa1)));
            short8 b0 = *(const short8*)(pb0 + ((kb & 0x100) | ((kb & 0xFF) ^ swb0)));
            short8 b1 = *(const short8*)(pb1 + ((kb & 0x100) | ((kb & 0xFF) ^ swb1)));
            acc00 = __builtin_amdgcn_mfma_f32_16x16x32_bf16(a0, b0, acc00, 0, 0, 0);
            acc01 = __builtin_amdgcn_mfma_f32_16x16x32_bf16(a0, b1, acc01, 0, 0, 0);
            acc10 = __builtin_amdgcn_mfma_f32_16x16x32_bf16(a1, b0, acc10, 0, 0, 0);
            acc11 = __builtin_amdgcn_mfma_f32_16x16x32_bf16(a1, b1, acc11, 0, 0, 0);
        }
    }
    const int crow = rb + wr + ((lane >> 4) << 2);
    const int ccol = cb + wc + lrow;
#pragma unroll
    for (int r = 0; r < 4; ++r) {
        Out[(crow + r) * C_SZ + ccol]           = acc00[r];
        Out[(crow + r) * C_SZ + ccol + 16]      = acc01[r];
        Out[(crow + 16 + r) * C_SZ + ccol]      = acc10[r];
        Out[(crow + 16 + r) * C_SZ + ccol + 16] = acc11[r];
    }
}

// Two rows per 512-thread block. Discount computed inline (__logf+fast div)
// instead of a divergent tab[] gather. Fixed softmax shift M=21.
__global__ __launch_bounds__(512) void k_rank_softmax(const float* __restrict__ sim,
                                                      const float* __restrict__ cosm,
                                                      const int* __restrict__ pos_count,
                                                      const float* __restrict__ tempPtr,
                                                      float* __restrict__ acc) {
    const int i0 = blockIdx.x << 1;
    __shared__ unsigned s_keys[2][C_SZ];          // 16 KB
    __shared__ unsigned short s_idx[2][C_SZ];     // 8 KB
    __shared__ unsigned s_hist[2][C_SZ / 2];      // 8 KB (2x u16 fields per word)
    __shared__ int s_wt[2][8];
    __shared__ float s_reds[2][8];
    __shared__ float s_diag[2];
    const int tid = threadIdx.x;     // 0..511
    const int lane = tid & 63;
    const int w = tid >> 6;          // 0..7
    const int base = tid << 2;       // 4 elems/thread/row
    const float M = 21.0f;
    const float temp = tempPtr[0];

    const bool v0 = pos_count[i0] != 0;
    const bool v1 = pos_count[i0 + 1] != 0;

    float4 sa0 = *(const float4*)&sim[i0 * C_SZ + base];
    float4 sa1 = *(const float4*)&sim[(i0 + 1) * C_SZ + base];
    float4 ca0 = *(const float4*)&cosm[i0 * C_SZ + base];
    float4 ca1 = *(const float4*)&cosm[(i0 + 1) * C_SZ + base];
    {
        uint4 z4 = {0u, 0u, 0u, 0u};
        ((uint4*)s_hist)[tid] = z4;
    }
    float xs0[4] = {sa0.x, sa0.y, sa0.z, sa0.w};
    float xs1[4] = {sa1.x, sa1.y, sa1.z, sa1.w};
    unsigned uk0[4], uk1[4];
    int bk0[4], bk1[4];
#pragma unroll
    for (int e = 0; e < 4; ++e) {
        unsigned u = __float_as_uint(xs0[e]);
        u = (u & 0x80000000u) ? ~u : (u | 0x80000000u);
        if (u == 0x7FFFFFFFu) u = 0x80000000u;
        uk0[e] = u;
        int b = (int)((xs0[e] + 0.5f) * 2047.0f);
        bk0[e] = b < 0 ? 0 : (b > 2047 ? 2047 : b);
        unsigned u1 = __float_as_uint(xs1[e]);
        u1 = (u1 & 0x80000000u) ? ~u1 : (u1 | 0x80000000u);
        if (u1 == 0x7FFFFFFFu) u1 = 0x80000000u;
        uk1[e] = u1;
        int b1 = (int)((xs1[e] + 0.5f) * 2047.0f);
        bk1[e] = b1 < 0 ? 0 : (b1 > 2047 ? 2047 : b1);
    }
    __syncthreads();
    if (v0) {
#pragma unroll
        for (int e = 0; e < 4; ++e)
            atomicAdd(&s_hist[0][bk0[e] >> 1], 1u << ((bk0[e] & 1) << 4));
    }
    if (v1) {
#pragma unroll
        for (int e = 0; e < 4; ++e)
            atomicAdd(&s_hist[1][bk1[e] >> 1], 1u << ((bk1[e] & 1) << 4));
    }
    __syncthreads();
    unsigned w00 = s_hist[0][2 * tid], w01 = s_hist[0][2 * tid + 1];
    unsigned w10 = s_hist[1][2 * tid], w11 = s_hist[1][2 * tid + 1];
    unsigned c00 = w00 & 0xFFFF, c01 = w00 >> 16, c02 = w01 & 0xFFFF, c03 = w01 >> 16;
    unsigned c10 = w10 & 0xFFFF, c11 = w10 >> 16, c12 = w11 & 0xFFFF, c13 = w11 >> 16;
    unsigned sum0 = c00 + c01 + c02 + c03;
    unsigned sum1 = c10 + c11 + c12 + c13;
    int incl0 = (int)sum0, incl1 = (int)sum1;
#pragma unroll
    for (int off = 1; off < 64; off <<= 1) {
        int o0 = __shfl_up(incl0, off);
        int o1 = __shfl_up(incl1, off);
        if (lane >= off) { incl0 += o0; incl1 += o1; }
    }
    if (lane == 63) { s_wt[0][w] = incl0; s_wt[1][w] = incl1; }
    __syncthreads();
    int wb0 = 0, wb1 = 0;
#pragma unroll
    for (int ww = 0; ww < 8; ++ww) {
        wb0 += (ww < w) ? s_wt[0][ww] : 0;
        wb1 += (ww < w) ? s_wt[1][ww] : 0;
    }
    unsigned eb0 = (unsigned)(wb0 + incl0 - (int)sum0);
    unsigned eb1 = (unsigned)(wb1 + incl1 - (int)sum1);
    {
        unsigned e00 = eb0, e01 = eb0 + c00, e02 = eb0 + c00 + c01, e03 = eb0 + c00 + c01 + c02;
        s_hist[0][2 * tid]     = e00 | (e01 << 16);
        s_hist[0][2 * tid + 1] = e02 | (e03 << 16);
        unsigned e10 = eb1, e11 = eb1 + c10, e12 = eb1 + c10 + c11, e13 = eb1 + c10 + c11 + c12;
        s_hist[1][2 * tid]     = e10 | (e11 << 16);
        s_hist[1][2 * tid + 1] = e12 | (e13 << 16);
    }
    __syncthreads();
    if (v0) {
#pragma unroll
        for (int e = 0; e < 4; ++e) {
            int sh = (bk0[e] & 1) << 4;
            unsigned old = atomicAdd(&s_hist[0][bk0[e] >> 1], 1u << sh);
            unsigned pos = (old >> sh) & 0xFFFFu;
            s_keys[0][pos] = uk0[e];
            s_idx[0][pos] = (unsigned short)(base + e);
        }
    }
    if (v1) {
#pragma unroll
        for (int e = 0; e < 4; ++e) {
            int sh = (bk1[e] & 1) << 4;
            unsigned old = atomicAdd(&s_hist[1][bk1[e] >> 1], 1u << sh);
            unsigned pos = (old >> sh) & 0xFFFFu;
            s_keys[1][pos] = uk1[e];
            s_idx[1][pos] = (unsigned short)(base + e);
        }
    }
    __syncthreads();
    // rank + logits + partial expsum (fixed shift M, inline discount)
    float ls0 = 0.f, ls1 = 0.f;
    float cs0[4] = {ca0.x, ca0.y, ca0.z, ca0.w};
    float cs1[4] = {ca1.x, ca1.y, ca1.z, ca1.w};
    if (v0) {
        float lg0[4];
#pragma unroll
        for (int e = 0; e < 4; ++e) {
            int b = bk0[e];
            unsigned endv = (s_hist[0][b >> 1] >> ((b & 1) << 4)) & 0xFFFFu;
            unsigned startv = b ? ((s_hist[0][(b - 1) >> 1] >> (((b - 1) & 1) << 4)) & 0xFFFFu) : 0u;
            unsigned mk = uk0[e];
            int less = 0, eq = 0;
            for (unsigned j = startv; j < endv; ++j) {
                unsigned kj = s_keys[0][j];
                less += (kj < mk) ? 1 : 0;
                eq += (kj == mk) ? 1 : 0;
            }
            if (eq > 1) {
                unsigned myi = (unsigned)(base + e);
                for (unsigned j = startv; j < endv; ++j)
                    if (s_keys[0][j] == mk && (unsigned)s_idx[0][j] < myi) less++;
            }
            int rk = (int)startv + less;
            float den = temp * __logf((float)rk + 2.0f);
            lg0[e] = __fdividef(cs0[e], den);
            ls0 += __expf(lg0[e] - M);
        }
        if ((i0 >> 2) == tid) {
            int ei = i0 & 3;
            float dv = lg0[0];
#pragma unroll
            for (int e = 1; e < 4; ++e) dv = (ei == e) ? lg0[e] : dv;
            s_diag[0] = dv;
        }
    }
    if (v1) {
        float lg1[4];
#pragma unroll
        for (int e = 0; e < 4; ++e) {
            int b = bk1[e];
            unsigned endv = (s_hist[1][b >> 1] >> ((b & 1) << 4)) & 0xFFFFu;
            unsigned startv = b ? ((s_hist[1][(b - 1) >> 1] >> (((b - 1) & 1) << 4)) & 0xFFFFu) : 0u;
            unsigned mk = uk1[e];
            int less = 0, eq = 0;
            for (unsigned j = startv; j < endv; ++j) {
                unsigned kj = s_keys[1][j];
                less += (kj < mk) ? 1 : 0;
                eq += (kj == mk) ? 1 : 0;
            }
            if (eq > 1) {
                unsigned myi = (unsigned)(base + e);
                for (unsigned j = startv; j < endv; ++j)
                    if (s_keys[1][j] == mk && (unsigned)s_idx[1][j] < myi) less++;
            }
            int rk = (int)startv + less;
            float den = temp * __logf((float)rk + 2.0f);
            lg1[e] = __fdividef(cs1[e], den);
            ls1 += __expf(lg1[e] - M);
        }
        if (((i0 + 1) >> 2) == tid) {
            int ei = (i0 + 1) & 3;
            float dv = lg1[0];
#pragma unroll
            for (int e = 1; e < 4; ++e) dv = (ei == e) ? lg1[e] : dv;
            s_diag[1] = dv;
        }
    }
#pragma unroll
    for (int off = 1; off < 64; off <<= 1) {
        ls0 += __shfl_xor(ls0, off);
        ls1 += __shfl_xor(ls1, off);
    }
    if (lane == 0) { s_reds[0][w] = ls0; s_reds[1][w] = ls1; }
    __syncthreads();
    if (tid == 0) {
        float t0 = 0.f, t1 = 0.f;
#pragma unroll
        for (int ww = 0; ww < 8; ++ww) { t0 += s_reds[0][ww]; t1 += s_reds[1][ww]; }
        float lp = 0.f, nv = 0.f;
        if (v0) { lp += -(s_diag[0] - M - logf(t0)); nv += 1.f; }
        if (v1) { lp += -(s_diag[1] - M - logf(t1)); nv += 1.f; }
        if (nv > 0.f) {
            atomicAdd(&acc[0], lp);
            atomicAdd(&acc[1], nv);
        }
    }
}

__global__ void k_final(const float* __restrict__ acc, float* __restrict__ out) {
    out[0] = acc[0] / fmaxf(acc[1], 1.0f);
}

extern "C" void kernel_launch(void* const* d_in, const int* in_sizes, int n_in,
                              void* d_out, int out_size, void* d_ws, size_t ws_size,
                              hipStream_t stream) {
    const float* output    = (const float*)d_in[0];
    const float* class_emb = (const float*)d_in[1];
    const float* targets   = (const float*)d_in[2];
    const float* tempPtr   = (const float*)d_in[3];
    float* out = (float*)d_out;
    char* ws = (char*)d_ws;

    int*   pos_count = (int*)(ws + 0);
    float* acc       = (float*)(ws + 8192);
    int*   pos_list  = (int*)(ws + 8448);
    __hip_bfloat16* pnh = (__hip_bfloat16*)(ws + 2105600);
    __hip_bfloat16* pnl = (__hip_bfloat16*)(ws + 2629888);
    __hip_bfloat16* enh = (__hip_bfloat16*)(ws + 3154176);
    __hip_bfloat16* enl = (__hip_bfloat16*)(ws + 3678464);
    float* sim       = (float*)(ws + 4210944);
    float* cosm      = (float*)(ws + 20988160);

    k_pre<<<9, 256, 0, stream>>>((unsigned*)ws);
    k_scan<<<SCAN_BLOCKS + C_SZ / 2, 256, 0, stream>>>(targets, class_emb,
                                                       pos_count, pos_list, enh, enl);
    k_pool<<<C_SZ, 256, 0, stream>>>(output, pos_count, pos_list, pnh, pnl);
    dim3 g(C_SZ / 64, 2 * C_SZ / 64);
    k_gemm_mfma<<<g, 256, 65536, stream>>>(enh, enl, pnh, pnl, sim, cosm);
    k_rank_softmax<<<C_SZ / 2, 512, 0, stream>>>(sim, cosm, pos_count, tempPtr, acc);
    k_final<<<1, 1, 0, stream>>>(acc, out);
}